// Round 10
// baseline (384.683 us; speedup 1.0000x reference)
//
#include <hip/hip_runtime.h>

#define BS 256

// ---- problem dims ----
constexpr int D1=41, H1=200, W1=176; constexpr int N1v=D1*H1*W1;   // 1,443,200
constexpr int D2=21, H2=100, W2=88;  constexpr int N2v=D2*H2*W2;   //   184,800
constexpr int D3=11, H3=50,  W3=44;  constexpr int N3v=D3*H3*W3;   //    24,200
constexpr int D4=5,  H4=25,  W4=22;  constexpr int N4v=D4*H4*W4;   //     2,750
constexpr int DOo=2, HOo=25, WOo=22;                                // out spatial
constexpr int ROWS1=40960;   // cap on level-1 active sites (actual ~28.9k)

typedef __attribute__((ext_vector_type(8))) short bf16x8;
typedef __attribute__((ext_vector_type(4))) float f32x4;

// ---- bf16 helpers ----
__device__ __forceinline__ float bflo(unsigned int u){ return __uint_as_float(u<<16); }
__device__ __forceinline__ float bfhi(unsigned int u){ return __uint_as_float(u & 0xffff0000u); }
__device__ __forceinline__ unsigned short f2bf(float f){
  unsigned int x = __float_as_uint(f);
  x += 0x7fffu + ((x>>16)&1u);             // round-to-nearest-even
  return (unsigned short)(x>>16);
}
__device__ __forceinline__ void acc8(float& acc, uint4 p, const float* __restrict__ wk, int stride){
  acc = fmaf(bflo(p.x), wk[0*stride], acc);
  acc = fmaf(bfhi(p.x), wk[1*stride], acc);
  acc = fmaf(bflo(p.y), wk[2*stride], acc);
  acc = fmaf(bfhi(p.y), wk[3*stride], acc);
  acc = fmaf(bflo(p.z), wk[4*stride], acc);
  acc = fmaf(bfhi(p.z), wk[5*stride], acc);
  acc = fmaf(bflo(p.w), wk[6*stride], acc);
  acc = fmaf(bfhi(p.w), wk[7*stride], acc);
}

// ---- weight-prep parameter pack (BN folded) ----
// mode 0: f32, layout [k][ci][o]                 (layers 0, 11)
// mode 2: bf16 tap-pair packed [p][o][32]        (layers 1, 2 — l1 MFMA)
// mode 3: bf16 supertap [dzdy][o][dx*CIN+ci]     (layers 3..10 — dense MFMA)
struct PrepArgs {
  const float* w[12]; const float* bn[12];
  void* dst[12]; float* bias[12];
  int O[12], I[12], K[12], mode[12];
  int off[13];
};

// ---- FUSED: weight prep (blocks [0,prepB)) + level-1 compaction w/ m2 scatter ----
__global__ void prep_and_list_kernel(PrepArgs a, int prepB,
                                     const float* __restrict__ mask,
                                     const float* __restrict__ x,
                                     unsigned short* __restrict__ xcl,
                                     int* __restrict__ I1, int* __restrict__ list1,
                                     int* __restrict__ cnt, float* __restrict__ m2){
  if ((int)blockIdx.x < prepB){
    int t = blockIdx.x*BS + threadIdx.x;
    if (t >= a.off[12]) return;
    int li = 0;
    while (t >= a.off[li+1]) li++;
    int e = t - a.off[li];
    int O=a.O[li], I=a.I[li], K=a.K[li], mode=a.mode[li];
    const float* w = a.w[li]; const float* bn = a.bn[li];
    if (mode == 2){
      int p = e/(O*32); int rem = e - p*(O*32); int o = rem>>5; int kk = rem&31;
      int tap = 2*p + (kk>=16 ? 1 : 0); int ci = kk&15;
      float g=bn[o], b=bn[O+o], m=bn[2*O+o], v=bn[3*O+o];
      float sc = g*rsqrtf(v+1e-3f);
      float val = (tap < 27) ? w[(o*I+ci)*K + tap]*sc : 0.f;
      ((unsigned short*)a.dst[li])[e] = f2bf(val);
      if (p==0 && kk==0) a.bias[li][o] = b - m*sc;
    } else if (mode == 3){
      int ci = e % I; int tmp = e / I; int dx = tmp % 3; tmp /= 3; int o = tmp % O; int g9 = tmp / O;
      float g=bn[o], b=bn[O+o], m=bn[2*O+o], v=bn[3*O+o];
      float sc = g*rsqrtf(v+1e-3f);
      int tap = g9*3 + dx;
      ((unsigned short*)a.dst[li])[e] = f2bf(w[(o*I+ci)*27 + tap]*sc);
      if (g9==0 && dx==0 && ci==0) a.bias[li][o] = b - m*sc;
    } else {
      int k = e % K; int rest = e / K; int ci = rest % I; int o = rest / I;
      float g=bn[o], b=bn[O+o], m=bn[2*O+o], v=bn[3*O+o];
      float sc = g*rsqrtf(v+1e-3f);
      ((float*)a.dst[li])[(k*I+ci)*O + o] = w[(o*I+ci)*K + k]*sc;
      if (ci==0 && k==0) a.bias[li][o] = b - m*sc;
    }
    return;
  }
  // ---- level-1 compaction + x->channel-last + m2 scatter ----
  constexpr int PER = 16;
  __shared__ int sc_[BS]; __shared__ int sbase;
  int b = blockIdx.x - prepB, t = threadIdx.x;
  int base_s = b*BS*PER;
  unsigned int bits = 0; int c = 0;
  #pragma unroll
  for (int i=0;i<PER;i++){
    int s = base_s + i*BS + t;
    bool act = false;
    if (s < N1v){
      act = mask[s] > 0.f;
      unsigned short h0 = f2bf(x[s]),       h1 = f2bf(x[N1v+s]);
      unsigned short h2 = f2bf(x[2*N1v+s]), h3 = f2bf(x[3*N1v+s]);
      uint2 pk; pk.x = ((unsigned)h1<<16)|h0; pk.y = ((unsigned)h3<<16)|h2;
      *(uint2*)(xcl + (size_t)s*4) = pk;
    }
    bits |= (act?1u:0u) << i; c += act;
  }
  sc_[t] = c;
  __syncthreads();
  for (int ofs=1; ofs<BS; ofs<<=1){
    int v = (t>=ofs) ? sc_[t-ofs] : 0;
    __syncthreads();
    sc_[t] += v;
    __syncthreads();
  }
  if (t == BS-1) sbase = atomicAdd(cnt, sc_[t]);
  __syncthreads();
  int pos = sbase + sc_[t] - c;
  #pragma unroll
  for (int i=0;i<PER;i++){
    if (bits & (1u<<i)){
      int s = base_s + i*BS + t;
      list1[pos] = s; I1[s] = pos+1; pos++;
      int zz = s/(H1*W1); int rem = s - zz*(H1*W1); int yy = rem/W1; int xx = rem - yy*W1;
      int az = zz+1, ay = yy+1, ax = xx+1;
      int zlo = (az-2) <= 0 ? 0 : (az-1)/2;  int zhi = min(D2-1, az/2);
      int ylo = (ay-2) <= 0 ? 0 : (ay-1)/2;  int yhi = min(H2-1, ay/2);
      int xlo = (ax-2) <= 0 ? 0 : (ax-1)/2;  int xhi = min(W2-1, ax/2);
      for (int zo=zlo; zo<=zhi; zo++)
        for (int yo=ylo; yo<=yhi; yo++)
          for (int xo=xlo; xo<=xhi; xo++)
            m2[(zo*H2+yo)*W2+xo] = 1.f;
    }
  }
}

// ---- compact 0/1 mask grid into a list; optionally scatter next-level mask ----
template<int N,int HI,int WI,int DON,int HON,int WON,int PZ,int PY,int PX,bool SCAT>
__global__ void compact_mask_kernel(const float* __restrict__ mout,
                                    int* __restrict__ list, int* __restrict__ cnt1,
                                    float* __restrict__ mnext){
  __shared__ int sc[BS]; __shared__ int sbase;
  int b = blockIdx.x, t = threadIdx.x;
  int s = b*BS + t;
  bool act = (s < N) && (mout[s] > 0.f);
  int c = act ? 1 : 0;
  sc[t] = c;
  __syncthreads();
  for (int ofs=1; ofs<BS; ofs<<=1){
    int v = (t>=ofs) ? sc[t-ofs] : 0;
    __syncthreads();
    sc[t] += v;
    __syncthreads();
  }
  if (t == BS-1) sbase = atomicAdd(cnt1, sc[t]);
  __syncthreads();
  if (act){
    list[sbase + sc[t] - 1] = s;
    if (SCAT){
      int zz = s/(HI*WI); int rem = s - zz*(HI*WI); int yy = rem/WI; int xx = rem - yy*WI;
      int az = zz+PZ, ay = yy+PY, ax = xx+PX;
      int zlo = (az-2) <= 0 ? 0 : (az-1)/2;  int zhi = min(DON-1, az/2);
      int ylo = (ay-2) <= 0 ? 0 : (ay-1)/2;  int yhi = min(HON-1, ay/2);
      int xlo = (ax-2) <= 0 ? 0 : (ax-1)/2;  int xhi = min(WON-1, ax/2);
      for (int zo=zlo; zo<=zhi; zo++)
        for (int yo=ylo; yo<=yhi; yo++)
          for (int xo=xlo; xo<=xhi; xo++)
            mnext[(zo*HON+yo)*WON+xo] = 1.f;
    }
  }
}

// ---- layer 0: subm conv 4->16, one THREAD per row, channel-last bf16 input ----
__global__ void subm_l0_kernel(const unsigned short* __restrict__ xcl,
                               const int* __restrict__ list1, const int* __restrict__ cnt,
                               const float* __restrict__ wt, const float* __restrict__ bias,
                               unsigned short* __restrict__ fout){
  __shared__ float Wl[27*4*16];
  __shared__ float Bl[16];
  int t = threadIdx.x;
  for (int e=t; e<27*4*16; e+=BS) Wl[e] = wt[e];
  if (t < 16) Bl[t] = bias[t];
  __syncthreads();
  int row = blockIdx.x*BS + t;
  if (row >= cnt[0]) return;
  int s = list1[row];
  int z = s/(H1*W1); int r = s - z*(H1*W1); int y = r/W1; int xx = r - y*W1;
  float acc[16];
  #pragma unroll
  for (int o=0;o<16;o++) acc[o] = Bl[o];
  #pragma unroll
  for (int dz=-1; dz<=1; dz++){ int zz=z+dz; if ((unsigned)zz >= (unsigned)D1) continue;
    #pragma unroll
    for (int dy=-1; dy<=1; dy++){ int yy=y+dy; if ((unsigned)yy >= (unsigned)H1) continue;
      #pragma unroll
      for (int dx=-1; dx<=1; dx++){ int xc=xx+dx; if ((unsigned)xc >= (unsigned)W1) continue;
        int ns = (zz*H1+yy)*W1+xc;
        int k = ((dz+1)*3+(dy+1))*3+(dx+1);
        uint2 pk = *(const uint2*)(xcl + (size_t)ns*4);
        float x0 = bflo(pk.x), x1 = bfhi(pk.x), x2 = bflo(pk.y), x3 = bfhi(pk.y);
        const float* wk = Wl + k*64;
        #pragma unroll
        for (int o=0;o<16;o++)
          acc[o] = fmaf(x0, wk[o], fmaf(x1, wk[16+o], fmaf(x2, wk[32+o], fmaf(x3, wk[48+o], acc[o]))));
      }}}
  #pragma unroll
  for (int o=0;o<16;o++) fout[row*16+o] = f2bf(fmaxf(acc[o], 0.f));
}

// ---- ONE-WAVE level-1 MFMA conv: 64-thread block = 1 independent wave, 16 rows.
//      No LDS, no barriers; B direct from global (L2-broadcast); A+B depth-1 pipelined. ----
template<int COUT,int HO,int WO,int PZ,int PY,int PX,int STR,bool DENSE_OUT>
__global__ __launch_bounds__(64)
void conv_w1_kernel(const unsigned short* __restrict__ fin,   // compact [row][16]
                    const int* __restrict__ I1,
                    const int* __restrict__ list, const int* __restrict__ cnt, int cidx,
                    const unsigned short* __restrict__ wbt,   // [14][COUT][32]
                    const float* __restrict__ bias,
                    unsigned short* __restrict__ outp){
  constexpr int NT = COUT/16;
  int nrows = cnt[cidx];
  int row0 = blockIdx.x*16;
  if (row0 >= nrows) return;

  int lane = threadIdx.x;
  int m = lane & 15, quad = lane >> 4;

  int row = row0 + m;
  bool rv = row < nrows;
  int z=0, y=0, x=0;
  {
    int s = list[rv ? row : row0];
    z = s/(HO*WO); int rem = s - z*(HO*WO); y = rem/WO; x = rem - y*WO;
  }

  // hoist ALL I1 lookups (independent, one latency)
  int rr[14];
  #pragma unroll
  for (int p=0;p<14;p++){
    int tap = 2*p + (quad>>1);
    rr[p] = 0;
    if (rv && tap < 27){
      int dz = tap/9, rem = tap - dz*9, dy = rem/3, dx = rem - dy*3;
      int zz = STR*z - PZ + dz, yy = STR*y - PY + dy, xx = STR*x - PX + dx;
      if ((unsigned)zz < (unsigned)D1 && (unsigned)yy < (unsigned)H1 && (unsigned)xx < (unsigned)W1)
        rr[p] = I1[(zz*H1+yy)*W1+xx];
    }
  }

  f32x4 acc[NT];
  #pragma unroll
  for (int i=0;i<NT;i++) acc[i] = (f32x4){0.f,0.f,0.f,0.f};

  bf16x8 acur = (bf16x8){0,0,0,0,0,0,0,0};
  if (rr[0] > 0) acur = *(const bf16x8*)(fin + (size_t)(rr[0]-1)*16 + (quad&1)*8);
  bf16x8 bcur[NT];
  #pragma unroll
  for (int nt=0; nt<NT; nt++)
    bcur[nt] = *(const bf16x8*)(wbt + (size_t)(nt*16 + m)*32 + quad*8);

  #pragma unroll
  for (int p=0;p<14;p++){
    bf16x8 anext = (bf16x8){0,0,0,0,0,0,0,0};
    bf16x8 bnext[NT];
    if (p < 13){
      if (rr[p+1] > 0)
        anext = *(const bf16x8*)(fin + (size_t)(rr[p+1]-1)*16 + (quad&1)*8);
      #pragma unroll
      for (int nt=0; nt<NT; nt++)
        bnext[nt] = *(const bf16x8*)(wbt + (size_t)((p+1)*COUT + nt*16 + m)*32 + quad*8);
    }
    #pragma unroll
    for (int nt=0; nt<NT; nt++)
      acc[nt] = __builtin_amdgcn_mfma_f32_16x16x32_bf16(acur, bcur[nt], acc[nt], 0, 0, 0);
    if (p < 13){
      acur = anext;
      #pragma unroll
      for (int nt=0; nt<NT; nt++) bcur[nt] = bnext[nt];
    }
  }

  #pragma unroll
  for (int nt=0; nt<NT; nt++){
    int cout = nt*16 + m;
    float bv = bias[cout];
    #pragma unroll
    for (int rg=0; rg<4; rg++){
      int rw = row0 + quad*4 + rg;
      if (rw < nrows){
        float v = fmaxf(acc[nt][rg] + bv, 0.f);
        if (DENSE_OUT){
          int s = list[rw];
          outp[(size_t)s*COUT + cout] = f2bf(v);
        } else {
          outp[(size_t)rw*COUT + cout] = f2bf(v);
        }
      }
    }
  }
}

// ---- ONE-WAVE dense-grid supertap MFMA conv (level-2 subm, CIN=COUT=32).
//      64-thread block, no LDS/barriers, A+B depth-1 pipelined, B direct global. ----
template<int CIN,int COUT,int DI,int HI,int WI,int PZ,int PY,int PX>
__global__ __launch_bounds__(64)
void conv_w2_kernel(const unsigned short* __restrict__ gin,
                    const int* __restrict__ list, const int* __restrict__ cnt, int cidx,
                    const unsigned short* __restrict__ wg,    // [9][COUT][3*CIN]
                    const float* __restrict__ bias,
                    unsigned short* __restrict__ gout){
  constexpr int KW = 3*CIN;
  constexpr int NT = COUT/16;
  constexpr int KT = KW/32;
  int nrows = cnt[cidx];
  int row0 = blockIdx.x*16;
  if (row0 >= nrows) return;

  int lane = threadIdx.x;
  int m = lane & 15, quad = lane >> 4;

  int row = row0 + m;
  bool rv = row < nrows;
  int z=0, y=0, x=0;
  {
    int s = list[rv ? row : row0];
    z = s/(HI*WI); int rem = s - z*(HI*WI); y = rem/WI; x = rem - y*WI;
  }

  auto loadA = [&](int g, bf16x8* av){
    int dz = g/3, dy = g - dz*3;
    int zz = z - PZ + dz, yy = y - PY + dy, xx0 = x - PX;
    bool zyok = rv && (unsigned)zz < (unsigned)DI && (unsigned)yy < (unsigned)HI;
    int base = ((zz*HI + yy)*WI + xx0)*CIN;
    #pragma unroll
    for (int kt=0; kt<KT; kt++){
      int tapx = (kt*32)/CIN;
      av[kt] = (bf16x8){0,0,0,0,0,0,0,0};
      if (zyok && (unsigned)(xx0 + tapx) < (unsigned)WI)
        av[kt] = *(const bf16x8*)(gin + (size_t)(base + kt*32 + quad*8));
    }
  };
  auto loadB = [&](int g, bf16x8 bv[KT][NT]){
    const unsigned short* src = wg + (size_t)g*COUT*KW;
    #pragma unroll
    for (int kt=0; kt<KT; kt++)
      #pragma unroll
      for (int nt=0; nt<NT; nt++)
        bv[kt][nt] = *(const bf16x8*)(src + (size_t)(nt*16 + m)*KW + kt*32 + quad*8);
  };

  f32x4 acc[NT];
  #pragma unroll
  for (int i=0;i<NT;i++) acc[i] = (f32x4){0.f,0.f,0.f,0.f};

  bf16x8 a0[KT], a1[KT], b0[KT][NT], b1[KT][NT];
  loadA(0, a0); loadB(0, b0);

  #pragma unroll
  for (int g=0; g<9; g++){
    if (g < 8){ loadA(g+1, a1); loadB(g+1, b1); }
    #pragma unroll
    for (int kt=0; kt<KT; kt++)
      #pragma unroll
      for (int nt=0; nt<NT; nt++)
        acc[nt] = __builtin_amdgcn_mfma_f32_16x16x32_bf16(a0[kt], b0[kt][nt], acc[nt], 0, 0, 0);
    if (g < 8){
      #pragma unroll
      for (int kt=0; kt<KT; kt++){
        a0[kt] = a1[kt];
        #pragma unroll
        for (int nt=0; nt<NT; nt++) b0[kt][nt] = b1[kt][nt];
      }
    }
  }

  #pragma unroll
  for (int nt=0; nt<NT; nt++){
    int cout = nt*16 + m;
    float bv = bias[cout];
    #pragma unroll
    for (int rg=0; rg<4; rg++){
      int rw = row0 + quad*4 + rg;
      if (rw < nrows){
        int s = list[rw];
        gout[(size_t)s*COUT + cout] = f2bf(fmaxf(acc[nt][rg] + bv, 0.f));
      }
    }
  }
}

// ---- dense-grid MFMA conv, 64 rows/block, A+B pipelined by 1 (level-3 subm, CIN=64) ----
template<int CIN,int COUT,int DI,int HI,int WI,int HO,int WO,int PZ,int PY,int PX,int STR>
__global__ __launch_bounds__(256)
void conv_mfma2_kernel(const unsigned short* __restrict__ gin,
                       const int* __restrict__ list, const int* __restrict__ cnt, int cidx,
                       const unsigned short* __restrict__ wg,    // [9][COUT][3*CIN]
                       const float* __restrict__ bias,
                       unsigned short* __restrict__ gout){
  constexpr int KW = 3*CIN;
  constexpr int BP = KW + 8;
  constexpr int NT = COUT/16;
  constexpr int KT = KW/32;
  constexpr int PREN = (COUT*KW + BS*8 - 1)/(BS*8);
  __shared__ __align__(16) unsigned short B[2][COUT*BP];

  int nrows = cnt[cidx];
  int row0 = blockIdx.x*64;
  if (row0 >= nrows) return;

  int t = threadIdx.x;
  int lane = t & 63, wave = t >> 6;
  int m = lane & 15, quad = lane >> 4;

  #pragma unroll
  for (int i=0;i<PREN;i++){
    int e = t*8 + i*BS*8;
    if (e < COUT*KW){
      int n = e / KW, c = e - n*KW;
      *(uint4*)(&B[0][n*BP + c]) = *(const uint4*)(wg + e);
    }
  }

  int row = row0 + wave*16 + m;
  bool rv = row < nrows;
  int z=0, y=0, x=0;
  {
    int s = list[rv ? row : row0];
    z = s/(HO*WO); int rem = s - z*(HO*WO); y = rem/WO; x = rem - y*WO;
  }

  auto loadA = [&](int g, bf16x8* av){
    int dz = g/3, dy = g - dz*3;
    int zz = STR*z - PZ + dz, yy = STR*y - PY + dy, xx0 = STR*x - PX;
    bool zyok = rv && (unsigned)zz < (unsigned)DI && (unsigned)yy < (unsigned)HI;
    int base = ((zz*HI + yy)*WI + xx0)*CIN;
    #pragma unroll
    for (int kt=0; kt<KT; kt++){
      int tapx = (kt*32)/CIN;
      av[kt] = (bf16x8){0,0,0,0,0,0,0,0};
      if (zyok && (unsigned)(xx0 + tapx) < (unsigned)WI)
        av[kt] = *(const bf16x8*)(gin + (size_t)(base + kt*32 + quad*8));
    }
  };

  f32x4 acc[NT];
  #pragma unroll
  for (int i=0;i<NT;i++) acc[i] = (f32x4){0.f,0.f,0.f,0.f};

  bf16x8 acur[KT], anext[KT];
  loadA(0, acur);
  __syncthreads();

  #pragma unroll
  for (int g=0; g<9; g++){
    uint4 pre[PREN];
    if (g < 8){
      const unsigned short* src = wg + (size_t)(g+1)*COUT*KW;
      #pragma unroll
      for (int i=0;i<PREN;i++){
        int e = t*8 + i*BS*8;
        pre[i] = (e < COUT*KW) ? *(const uint4*)(src + e) : (uint4){0,0,0,0};
      }
      loadA(g+1, anext);
    }
    #pragma unroll
    for (int kt=0; kt<KT; kt++){
      #pragma unroll
      for (int nt=0; nt<NT; nt++){
        bf16x8 b = *(const bf16x8*)(&B[g&1][(nt*16 + m)*BP + kt*32 + quad*8]);
        acc[nt] = __builtin_amdgcn_mfma_f32_16x16x32_bf16(acur[kt], b, acc[nt], 0, 0, 0);
      }
    }
    if (g < 8){
      #pragma unroll
      for (int i=0;i<PREN;i++){
        int e = t*8 + i*BS*8;
        if (e < COUT*KW){
          int n = e / KW, c = e - n*KW;
          *(uint4*)(&B[(g+1)&1][n*BP + c]) = pre[i];
        }
      }
      #pragma unroll
      for (int kt=0; kt<KT; kt++) acur[kt] = anext[kt];
    }
    __syncthreads();
  }

  #pragma unroll
  for (int nt=0; nt<NT; nt++){
    int cout = nt*16 + m;
    float bv = bias[cout];
    #pragma unroll
    for (int rg=0; rg<4; rg++){
      int rw = row0 + wave*16 + quad*4 + rg;
      if (rw < nrows){
        int s = list[rw];
        gout[(size_t)s*COUT + cout] = f2bf(fmaxf(acc[nt][rg] + bv, 0.f));
      }
    }
  }
}

// ---- TAP-PARALLEL dense-grid MFMA conv: 16 rows/block, 4 waves over supertaps ----
template<int CIN,int COUT,int DI,int HI,int WI,int HO,int WO,int PZ,int PY,int PX,int STR>
__global__ __launch_bounds__(256)
void conv_tp_kernel(const unsigned short* __restrict__ gin,
                    const int* __restrict__ list, const int* __restrict__ cnt, int cidx,
                    const unsigned short* __restrict__ wg,    // [9][COUT][3*CIN]
                    const float* __restrict__ bias,
                    unsigned short* __restrict__ gout){
  constexpr int KW = 3*CIN;
  constexpr int NT = COUT/16;
  constexpr int KT = KW/32;
  __shared__ float R[4][NT*256];

  int nrows = cnt[cidx];
  int row0 = blockIdx.x*16;
  if (row0 >= nrows) return;

  int t = threadIdx.x;
  int lane = t & 63, wave = t >> 6;
  int m = lane & 15, quad = lane >> 4;

  int row = row0 + m;
  bool rv = row < nrows;
  int z=0, y=0, x=0;
  {
    int s = list[rv ? row : row0];
    z = s/(HO*WO); int rem = s - z*(HO*WO); y = rem/WO; x = rem - y*WO;
  }

  bf16x8 av[3][KT];
  #pragma unroll
  for (int i=0;i<3;i++){
    int g = wave + i*4;
    #pragma unroll
    for (int kt=0; kt<KT; kt++) av[i][kt] = (bf16x8){0,0,0,0,0,0,0,0};
    if (g < 9){
      int dz = g/3, dy = g - dz*3;
      int zz = STR*z - PZ + dz, yy = STR*y - PY + dy, xx0 = STR*x - PX;
      bool zyok = rv && (unsigned)zz < (unsigned)DI && (unsigned)yy < (unsigned)HI;
      int base = ((zz*HI + yy)*WI + xx0)*CIN;
      #pragma unroll
      for (int kt=0; kt<KT; kt++){
        int tapx = (kt*32)/CIN;
        if (zyok && (unsigned)(xx0 + tapx) < (unsigned)WI)
          av[i][kt] = *(const bf16x8*)(gin + (size_t)(base + kt*32 + quad*8));
      }
    }
  }

  f32x4 acc[NT];
  #pragma unroll
  for (int i=0;i<NT;i++) acc[i] = (f32x4){0.f,0.f,0.f,0.f};

  #pragma unroll
  for (int i=0;i<3;i++){
    int g = wave + i*4;
    if (g < 9){
      const unsigned short* wsrc = wg + (size_t)g*COUT*KW;
      #pragma unroll
      for (int kt=0; kt<KT; kt++){
        #pragma unroll
        for (int nt=0; nt<NT; nt++){
          bf16x8 b = *(const bf16x8*)(wsrc + (size_t)(nt*16 + m)*KW + kt*32 + quad*8);
          acc[nt] = __builtin_amdgcn_mfma_f32_16x16x32_bf16(av[i][kt], b, acc[nt], 0, 0, 0);
        }
      }
    }
  }

  #pragma unroll
  for (int nt=0; nt<NT; nt++)
    #pragma unroll
    for (int rg=0; rg<4; rg++)
      R[wave][nt*256 + (quad*4+rg)*16 + m] = acc[nt][rg];
  __syncthreads();

  for (int e = t; e < 16*COUT; e += BS){
    int r = e / COUT, cout = e % COUT;
    int nt = cout >> 4, mm = cout & 15;
    int idx = nt*256 + r*16 + mm;
    float sum = R[0][idx] + R[1][idx] + R[2][idx] + R[3][idx];
    int rw = row0 + r;
    if (rw < nrows){
      int s = list[rw];
      gout[(size_t)s*COUT + cout] = f2bf(fmaxf(sum + bias[cout], 0.f));
    }
  }
}

// ---- final: spconv 64->128, k=(3,1,1), stride=(2,1,1), pad 0; write [1,256,25,22] f32 ----
__global__ void conv_out_kernel(const unsigned short* __restrict__ g4,
                                const float* __restrict__ m4,
                                const float* __restrict__ wt, const float* __restrict__ bias,
                                float* __restrict__ out){
  int t = blockIdx.x*BS + threadIdx.x;
  if (t >= 128*DOo*HOo*WOo) return;
  int cout = t & 127; int s = t >> 7;
  int d = s/(HOo*WOo); int r = s - d*(HOo*WOo); int h = r/WOo; int w = r - h*WOo;
  float res = 0.f;
  bool act = false;
  float acc = bias[cout];
  for (int dz=0; dz<3; dz++){
    int z4 = 2*d + dz;
    int site = (z4*H4 + h)*W4 + w;
    if (m4[site] == 0.f) continue;
    act = true;
    const uint4* fr = (const uint4*)(g4 + (size_t)site*64);
    const float* wk = wt + dz*64*128 + cout;
    #pragma unroll
    for (int q=0; q<8; q++) acc8(acc, fr[q], wk + q*8*128, 128);
  }
  if (act) res = fmaxf(acc, 0.f);
  out[((cout*DOo + d)*HOo + h)*WOo + w] = res;
}

extern "C" void kernel_launch(void* const* d_in, const int* in_sizes, int n_in,
                              void* d_out, int out_size, void* d_ws, size_t ws_size,
                              hipStream_t stream){
  const float* x    = (const float*)d_in[0];
  const float* mask = (const float*)d_in[1];
  const float* w[12]; const float* bnp[12];
  for (int i=0;i<12;i++){ w[i]=(const float*)d_in[2+2*i]; bnp[i]=(const float*)d_in[3+2*i]; }

  char* base = (char*)d_ws; size_t off = 0;
  auto alloc = [&](size_t b)->void*{ void* p = base + off; off = (off + b + 255) & ~(size_t)255; return p; };

  // --- region zeroed every call (one memset) ---
  int* cnt   = (int*)alloc(16);                         // [c1,c2,c3,c4]
  int* I1    = (int*)alloc((size_t)N1v*4);              // site -> row+1 (0 = inactive)
  unsigned short* g2a = (unsigned short*)alloc((size_t)N2v*32*2);
  unsigned short* g2b = (unsigned short*)alloc((size_t)N2v*32*2);
  unsigned short* g3a = (unsigned short*)alloc((size_t)N3v*64*2);
  unsigned short* g3b = (unsigned short*)alloc((size_t)N3v*64*2);
  unsigned short* g4a = (unsigned short*)alloc((size_t)N4v*64*2);
  unsigned short* g4b = (unsigned short*)alloc((size_t)N4v*64*2);
  float* m2 = (float*)alloc((size_t)N2v*4);             // scatter-marked -> must be 0-init
  float* m3 = (float*)alloc((size_t)N3v*4);
  float* m4 = (float*)alloc((size_t)N4v*4);
  size_t zero_bytes = off;
  // --- fully-overwritten-before-read buffers ---
  unsigned short* xcl = (unsigned short*)alloc((size_t)N1v*4*2);  // channel-last bf16 x
  int* list1 = (int*)alloc((size_t)ROWS1*4);
  unsigned short* f1a = (unsigned short*)alloc((size_t)ROWS1*16*2);
  unsigned short* f1b = (unsigned short*)alloc((size_t)ROWS1*16*2);
  int* list2 = (int*)alloc((size_t)N2v*4);
  int* list3 = (int*)alloc((size_t)N3v*4);
  int* list4 = (int*)alloc((size_t)N4v*4);

  static const int Oa[12]={16,16,32,32,32,64,64,64,64,64,64,128};
  static const int Ia[12]={ 4,16,16,32,32,32,64,64,64,64,64, 64};
  static const int Ka[12]={27,27,27,27,27,27,27,27,27,27,27,  3};
  static const int Ma[12]={ 0, 2, 2, 3, 3, 3, 3, 3, 3, 3, 3,  0};  // prep mode
  float* wt[12]; float* bs[12]; unsigned short* wbt[12];
  for (int i=0;i<12;i++){
    bs[i] = (float*)alloc((size_t)Oa[i]*4);
    wt[i]=nullptr; wbt[i]=nullptr;
    if (Ma[i]==0)      wt[i]  = (float*)alloc((size_t)Oa[i]*Ia[i]*Ka[i]*4);
    else if (Ma[i]==3) wbt[i] = (unsigned short*)alloc((size_t)Oa[i]*Ia[i]*27*2);
    else               wbt[i] = (unsigned short*)alloc((size_t)14*Oa[i]*32*2);
  }

  hipMemsetAsync(base, 0, zero_bytes, stream);

  // fused weight prep + level-1 compaction (+ m2 scatter)
  PrepArgs pa;
  pa.off[0] = 0;
  for (int i=0;i<12;i++){
    pa.w[i]=w[i]; pa.bn[i]=bnp[i]; pa.bias[i]=bs[i];
    pa.O[i]=Oa[i]; pa.I[i]=Ia[i]; pa.K[i]=Ka[i]; pa.mode[i]=Ma[i];
    pa.dst[i] = (Ma[i]==0) ? (void*)wt[i] : (void*)wbt[i];
    int tot = (Ma[i]==2) ? 14*Oa[i]*32 : Oa[i]*Ia[i]*Ka[i];
    pa.off[i+1] = pa.off[i] + tot;
  }
  int prepB = (pa.off[12]+BS-1)/BS;
  int listB = (N1v + BS*16 - 1)/(BS*16);
  prep_and_list_kernel<<<prepB + listB, BS, 0, stream>>>(pa, prepB, mask, x, xcl, I1, list1, cnt, m2);

  // level 1: subm 4->16 (thread-per-row, channel-last), then subm 16->16 (one-wave MFMA)
  subm_l0_kernel<<<(ROWS1+BS-1)/BS, BS, 0, stream>>>(xcl, list1, cnt, wt[0], bs[0], f1a);
  conv_w1_kernel<16,H1,W1,1,1,1,1,false><<<ROWS1/16, 64, 0, stream>>>
      (f1a, I1, list1, cnt, 0, wbt[1], bs[1], f1b);

  // level-2 list (+ m3 scatter), then spconv 16->32 (one-wave) into zeroed dense grid
  compact_mask_kernel<N2v,H2,W2,D3,H3,W3,1,1,1,true><<<(N2v+BS-1)/BS, BS, 0, stream>>>(m2, list2, cnt+1, m3);
  conv_w1_kernel<32,H2,W2,1,1,1,2,true><<<(N2v+15)/16, 64, 0, stream>>>
      (f1b, I1, list2, cnt, 1, wbt[2], bs[2], g2a);

  // level-2 subm convs (one-wave supertap MFMA), 32ch
  {
    int nb = (N2v + 15)/16;
    conv_w2_kernel<32,32,D2,H2,W2,1,1,1><<<nb, 64, 0, stream>>>(g2a, list2, cnt, 1, wbt[3], bs[3], g2b);
    conv_w2_kernel<32,32,D2,H2,W2,1,1,1><<<nb, 64, 0, stream>>>(g2b, list2, cnt, 1, wbt[4], bs[4], g2a);
  }

  // level-3 list (+ m4 scatter); spconv (tap-parallel) + subm convs (64-row)
  compact_mask_kernel<N3v,H3,W3,D4,H4,W4,0,1,1,true><<<(N3v+BS-1)/BS, BS, 0, stream>>>(m3, list3, cnt+2, m4);
  {
    conv_tp_kernel<32,64,D2,H2,W2,H3,W3,1,1,1,2><<<(N3v+15)/16, 256, 0, stream>>>(g2a, list3, cnt, 2, wbt[5], bs[5], g3a);
    int nb = (N3v + 63)/64;
    conv_mfma2_kernel<64,64,D3,H3,W3,H3,W3,1,1,1,1><<<nb, 256, 0, stream>>>(g3a, list3, cnt, 2, wbt[6], bs[6], g3b);
    conv_mfma2_kernel<64,64,D3,H3,W3,H3,W3,1,1,1,1><<<nb, 256, 0, stream>>>(g3b, list3, cnt, 2, wbt[7], bs[7], g3a);
  }

  // level-4 list; all level-4 convs tap-parallel
  compact_mask_kernel<N4v,H4,W4,1,1,1,0,0,0,false><<<(N4v+BS-1)/BS, BS, 0, stream>>>(m4, list4, cnt+3, nullptr);
  {
    int nb = (N4v + 15)/16;
    conv_tp_kernel<64,64,D3,H3,W3,H4,W4,0,1,1,2><<<nb, 256, 0, stream>>>(g3a, list4, cnt, 3, wbt[8], bs[8], g4a);
    conv_tp_kernel<64,64,D4,H4,W4,H4,W4,1,1,1,1><<<nb, 256, 0, stream>>>(g4a, list4, cnt, 3, wbt[9], bs[9], g4b);
    conv_tp_kernel<64,64,D4,H4,W4,H4,W4,1,1,1,1><<<nb, 256, 0, stream>>>(g4b, list4, cnt, 3, wbt[10], bs[10], g4a);
  }

  // final spconv (3,1,1)/(2,1,1)/pad0 -> [1,256,25,22]
  conv_out_kernel<<<(128*DOo*HOo*WOo)/BS, BS, 0, stream>>>(g4a, m4, wt[11], bs[11], (float*)d_out);
}

// Round 11
// 384.561 us; speedup vs baseline: 1.0003x; 1.0003x over previous
//
#include <hip/hip_runtime.h>

#define BS 256

// ---- problem dims ----
constexpr int D1=41, H1=200, W1=176; constexpr int N1v=D1*H1*W1;   // 1,443,200
constexpr int D2=21, H2=100, W2=88;  constexpr int N2v=D2*H2*W2;   //   184,800
constexpr int D3=11, H3=50,  W3=44;  constexpr int N3v=D3*H3*W3;   //    24,200
constexpr int D4=5,  H4=25,  W4=22;  constexpr int N4v=D4*H4*W4;   //     2,750
constexpr int DOo=2, HOo=25, WOo=22;                                // out spatial
constexpr int ROWS1=40960;   // cap on level-1 active sites (actual ~28.9k)

typedef __attribute__((ext_vector_type(8))) short bf16x8;
typedef __attribute__((ext_vector_type(4))) float f32x4;

// ---- bf16 helpers ----
__device__ __forceinline__ float bflo(unsigned int u){ return __uint_as_float(u<<16); }
__device__ __forceinline__ float bfhi(unsigned int u){ return __uint_as_float(u & 0xffff0000u); }
__device__ __forceinline__ unsigned short f2bf(float f){
  unsigned int x = __float_as_uint(f);
  x += 0x7fffu + ((x>>16)&1u);             // round-to-nearest-even
  return (unsigned short)(x>>16);
}
__device__ __forceinline__ void acc8(float& acc, uint4 p, const float* __restrict__ wk, int stride){
  acc = fmaf(bflo(p.x), wk[0*stride], acc);
  acc = fmaf(bfhi(p.x), wk[1*stride], acc);
  acc = fmaf(bflo(p.y), wk[2*stride], acc);
  acc = fmaf(bfhi(p.y), wk[3*stride], acc);
  acc = fmaf(bflo(p.z), wk[4*stride], acc);
  acc = fmaf(bfhi(p.z), wk[5*stride], acc);
  acc = fmaf(bflo(p.w), wk[6*stride], acc);
  acc = fmaf(bfhi(p.w), wk[7*stride], acc);
}

// ---- weight-prep parameter pack (BN folded) ----
// mode 0: f32, layout [k][ci][o]                 (layers 0, 11)
// mode 2: bf16 tap-pair packed [p][o][32]        (layers 1, 2 — l1 MFMA)
// mode 3: bf16 supertap [dzdy][o][dx*CIN+ci]     (layers 3..10 — dense MFMA)
struct PrepArgs {
  const float* w[12]; const float* bn[12];
  void* dst[12]; float* bias[12];
  int O[12], I[12], K[12], mode[12];
  int off[13];
};

// ---- FUSED: weight prep (blocks [0,prepB)) + level-1 compaction w/ m2 scatter ----
__global__ void prep_and_list_kernel(PrepArgs a, int prepB,
                                     const float* __restrict__ mask,
                                     const float* __restrict__ x,
                                     unsigned short* __restrict__ xcl,
                                     int* __restrict__ I1, int* __restrict__ list1,
                                     int* __restrict__ cnt, float* __restrict__ m2){
  if ((int)blockIdx.x < prepB){
    int t = blockIdx.x*BS + threadIdx.x;
    if (t >= a.off[12]) return;
    int li = 0;
    while (t >= a.off[li+1]) li++;
    int e = t - a.off[li];
    int O=a.O[li], I=a.I[li], K=a.K[li], mode=a.mode[li];
    const float* w = a.w[li]; const float* bn = a.bn[li];
    if (mode == 2){
      int p = e/(O*32); int rem = e - p*(O*32); int o = rem>>5; int kk = rem&31;
      int tap = 2*p + (kk>=16 ? 1 : 0); int ci = kk&15;
      float g=bn[o], b=bn[O+o], m=bn[2*O+o], v=bn[3*O+o];
      float sc = g*rsqrtf(v+1e-3f);
      float val = (tap < 27) ? w[(o*I+ci)*K + tap]*sc : 0.f;
      ((unsigned short*)a.dst[li])[e] = f2bf(val);
      if (p==0 && kk==0) a.bias[li][o] = b - m*sc;
    } else if (mode == 3){
      int ci = e % I; int tmp = e / I; int dx = tmp % 3; tmp /= 3; int o = tmp % O; int g9 = tmp / O;
      float g=bn[o], b=bn[O+o], m=bn[2*O+o], v=bn[3*O+o];
      float sc = g*rsqrtf(v+1e-3f);
      int tap = g9*3 + dx;
      ((unsigned short*)a.dst[li])[e] = f2bf(w[(o*I+ci)*27 + tap]*sc);
      if (g9==0 && dx==0 && ci==0) a.bias[li][o] = b - m*sc;
    } else {
      int k = e % K; int rest = e / K; int ci = rest % I; int o = rest / I;
      float g=bn[o], b=bn[O+o], m=bn[2*O+o], v=bn[3*O+o];
      float sc = g*rsqrtf(v+1e-3f);
      ((float*)a.dst[li])[(k*I+ci)*O + o] = w[(o*I+ci)*K + k]*sc;
      if (ci==0 && k==0) a.bias[li][o] = b - m*sc;
    }
    return;
  }
  // ---- level-1 compaction + x->channel-last + m2 scatter ----
  constexpr int PER = 16;
  __shared__ int sc_[BS]; __shared__ int sbase;
  int b = blockIdx.x - prepB, t = threadIdx.x;
  int base_s = b*BS*PER;
  unsigned int bits = 0; int c = 0;
  #pragma unroll
  for (int i=0;i<PER;i++){
    int s = base_s + i*BS + t;
    bool act = false;
    if (s < N1v){
      act = mask[s] > 0.f;
      unsigned short h0 = f2bf(x[s]),       h1 = f2bf(x[N1v+s]);
      unsigned short h2 = f2bf(x[2*N1v+s]), h3 = f2bf(x[3*N1v+s]);
      uint2 pk; pk.x = ((unsigned)h1<<16)|h0; pk.y = ((unsigned)h3<<16)|h2;
      *(uint2*)(xcl + (size_t)s*4) = pk;
    }
    bits |= (act?1u:0u) << i; c += act;
  }
  sc_[t] = c;
  __syncthreads();
  for (int ofs=1; ofs<BS; ofs<<=1){
    int v = (t>=ofs) ? sc_[t-ofs] : 0;
    __syncthreads();
    sc_[t] += v;
    __syncthreads();
  }
  if (t == BS-1) sbase = atomicAdd(cnt, sc_[t]);
  __syncthreads();
  int pos = sbase + sc_[t] - c;
  #pragma unroll
  for (int i=0;i<PER;i++){
    if (bits & (1u<<i)){
      int s = base_s + i*BS + t;
      list1[pos] = s; I1[s] = pos+1; pos++;
      int zz = s/(H1*W1); int rem = s - zz*(H1*W1); int yy = rem/W1; int xx = rem - yy*W1;
      int az = zz+1, ay = yy+1, ax = xx+1;
      int zlo = (az-2) <= 0 ? 0 : (az-1)/2;  int zhi = min(D2-1, az/2);
      int ylo = (ay-2) <= 0 ? 0 : (ay-1)/2;  int yhi = min(H2-1, ay/2);
      int xlo = (ax-2) <= 0 ? 0 : (ax-1)/2;  int xhi = min(W2-1, ax/2);
      for (int zo=zlo; zo<=zhi; zo++)
        for (int yo=ylo; yo<=yhi; yo++)
          for (int xo=xlo; xo<=xhi; xo++)
            m2[(zo*H2+yo)*W2+xo] = 1.f;
    }
  }
}

// ---- compact 0/1 mask grid into a list; optionally scatter next-level mask ----
template<int N,int HI,int WI,int DON,int HON,int WON,int PZ,int PY,int PX,bool SCAT>
__global__ void compact_mask_kernel(const float* __restrict__ mout,
                                    int* __restrict__ list, int* __restrict__ cnt1,
                                    float* __restrict__ mnext){
  __shared__ int sc[BS]; __shared__ int sbase;
  int b = blockIdx.x, t = threadIdx.x;
  int s = b*BS + t;
  bool act = (s < N) && (mout[s] > 0.f);
  int c = act ? 1 : 0;
  sc[t] = c;
  __syncthreads();
  for (int ofs=1; ofs<BS; ofs<<=1){
    int v = (t>=ofs) ? sc[t-ofs] : 0;
    __syncthreads();
    sc[t] += v;
    __syncthreads();
  }
  if (t == BS-1) sbase = atomicAdd(cnt1, sc[t]);
  __syncthreads();
  if (act){
    list[sbase + sc[t] - 1] = s;
    if (SCAT){
      int zz = s/(HI*WI); int rem = s - zz*(HI*WI); int yy = rem/WI; int xx = rem - yy*WI;
      int az = zz+PZ, ay = yy+PY, ax = xx+PX;
      int zlo = (az-2) <= 0 ? 0 : (az-1)/2;  int zhi = min(DON-1, az/2);
      int ylo = (ay-2) <= 0 ? 0 : (ay-1)/2;  int yhi = min(HON-1, ay/2);
      int xlo = (ax-2) <= 0 ? 0 : (ax-1)/2;  int xhi = min(WON-1, ax/2);
      for (int zo=zlo; zo<=zhi; zo++)
        for (int yo=ylo; yo<=yhi; yo++)
          for (int xo=xlo; xo<=xhi; xo++)
            mnext[(zo*HON+yo)*WON+xo] = 1.f;
    }
  }
}

// ---- layer 0: subm conv 4->16, one THREAD per row, channel-last bf16 input ----
__global__ void subm_l0_kernel(const unsigned short* __restrict__ xcl,
                               const int* __restrict__ list1, const int* __restrict__ cnt,
                               const float* __restrict__ wt, const float* __restrict__ bias,
                               unsigned short* __restrict__ fout){
  __shared__ float Wl[27*4*16];
  __shared__ float Bl[16];
  int t = threadIdx.x;
  for (int e=t; e<27*4*16; e+=BS) Wl[e] = wt[e];
  if (t < 16) Bl[t] = bias[t];
  __syncthreads();
  int row = blockIdx.x*BS + t;
  if (row >= cnt[0]) return;
  int s = list1[row];
  int z = s/(H1*W1); int r = s - z*(H1*W1); int y = r/W1; int xx = r - y*W1;
  float acc[16];
  #pragma unroll
  for (int o=0;o<16;o++) acc[o] = Bl[o];
  #pragma unroll
  for (int dz=-1; dz<=1; dz++){ int zz=z+dz; if ((unsigned)zz >= (unsigned)D1) continue;
    #pragma unroll
    for (int dy=-1; dy<=1; dy++){ int yy=y+dy; if ((unsigned)yy >= (unsigned)H1) continue;
      #pragma unroll
      for (int dx=-1; dx<=1; dx++){ int xc=xx+dx; if ((unsigned)xc >= (unsigned)W1) continue;
        int ns = (zz*H1+yy)*W1+xc;
        int k = ((dz+1)*3+(dy+1))*3+(dx+1);
        uint2 pk = *(const uint2*)(xcl + (size_t)ns*4);
        float x0 = bflo(pk.x), x1 = bfhi(pk.x), x2 = bflo(pk.y), x3 = bfhi(pk.y);
        const float* wk = Wl + k*64;
        #pragma unroll
        for (int o=0;o<16;o++)
          acc[o] = fmaf(x0, wk[o], fmaf(x1, wk[16+o], fmaf(x2, wk[32+o], fmaf(x3, wk[48+o], acc[o]))));
      }}}
  #pragma unroll
  for (int o=0;o<16;o++) fout[row*16+o] = f2bf(fmaxf(acc[o], 0.f));
}

// ---- TAP-PARALLEL level-1 MFMA conv: 16 rows/block, 4 waves split the 14 tap-pairs
//      (wave w -> pairs w, w+4, w+8, w+12). rr, A, B all hoisted -> ~2 exposed
//      latencies per block. LDS cross-wave reduction. ----
template<int COUT,int HO,int WO,int PZ,int PY,int PX,int STR,bool DENSE_OUT>
__global__ __launch_bounds__(256)
void conv_tp_l1_kernel(const unsigned short* __restrict__ fin,   // compact [row][16]
                       const int* __restrict__ I1,
                       const int* __restrict__ list, const int* __restrict__ cnt, int cidx,
                       const unsigned short* __restrict__ wbt,   // [14][COUT][32]
                       const float* __restrict__ bias,
                       unsigned short* __restrict__ outp){
  constexpr int NT = COUT/16;
  __shared__ float R[4][NT*256];
  int nrows = cnt[cidx];
  int row0 = blockIdx.x*16;
  if (row0 >= nrows) return;

  int t = threadIdx.x;
  int lane = t & 63, wave = t >> 6;
  int m = lane & 15, quad = lane >> 4;

  int row = row0 + m;
  bool rv = row < nrows;
  int z=0, y=0, x=0;
  {
    int s = list[rv ? row : row0];
    z = s/(HO*WO); int rem = s - z*(HO*WO); y = rem/WO; x = rem - y*WO;
  }

  // hoist rr lookups for this wave's pairs (independent, one latency)
  int rr[4];
  #pragma unroll
  for (int i=0;i<4;i++){
    int p = wave + i*4;
    rr[i] = 0;
    if (p < 14){
      int tap = 2*p + (quad>>1);
      if (rv && tap < 27){
        int dz = tap/9, rem = tap - dz*9, dy = rem/3, dx = rem - dy*3;
        int zz = STR*z - PZ + dz, yy = STR*y - PY + dy, xx = STR*x - PX + dx;
        if ((unsigned)zz < (unsigned)D1 && (unsigned)yy < (unsigned)H1 && (unsigned)xx < (unsigned)W1)
          rr[i] = I1[(zz*H1+yy)*W1+xx];
      }
    }
  }
  // hoist A and B (independent given rr: second latency)
  bf16x8 av[4]; bf16x8 bv[4][NT];
  #pragma unroll
  for (int i=0;i<4;i++){
    int p = wave + i*4;
    av[i] = (bf16x8){0,0,0,0,0,0,0,0};
    if (rr[i] > 0) av[i] = *(const bf16x8*)(fin + (size_t)(rr[i]-1)*16 + (quad&1)*8);
    #pragma unroll
    for (int nt=0; nt<NT; nt++){
      bv[i][nt] = (bf16x8){0,0,0,0,0,0,0,0};
      if (p < 14)
        bv[i][nt] = *(const bf16x8*)(wbt + (size_t)(p*COUT + nt*16 + m)*32 + quad*8);
    }
  }

  f32x4 acc[NT];
  #pragma unroll
  for (int i=0;i<NT;i++) acc[i] = (f32x4){0.f,0.f,0.f,0.f};

  #pragma unroll
  for (int i=0;i<4;i++){
    int p = wave + i*4;
    if (p < 14){
      #pragma unroll
      for (int nt=0; nt<NT; nt++)
        acc[nt] = __builtin_amdgcn_mfma_f32_16x16x32_bf16(av[i], bv[i][nt], acc[nt], 0, 0, 0);
    }
  }

  // cross-wave reduction in LDS
  #pragma unroll
  for (int nt=0; nt<NT; nt++)
    #pragma unroll
    for (int rg=0; rg<4; rg++)
      R[wave][nt*256 + (quad*4+rg)*16 + m] = acc[nt][rg];
  __syncthreads();

  for (int e = t; e < 16*COUT; e += BS){
    int r = e / COUT, cout = e % COUT;
    int nt = cout >> 4, mm = cout & 15;
    int idx = nt*256 + r*16 + mm;
    float sum = R[0][idx] + R[1][idx] + R[2][idx] + R[3][idx];
    int rw = row0 + r;
    if (rw < nrows){
      float v = fmaxf(sum + bias[cout], 0.f);
      if (DENSE_OUT){
        int s = list[rw];
        outp[(size_t)s*COUT + cout] = f2bf(v);
      } else {
        outp[(size_t)rw*COUT + cout] = f2bf(v);
      }
    }
  }
}

// ---- dense-grid MFMA conv, 64 rows/block, A+B pipelined by 1 (level-3 subm, CIN=64) ----
template<int CIN,int COUT,int DI,int HI,int WI,int HO,int WO,int PZ,int PY,int PX,int STR>
__global__ __launch_bounds__(256)
void conv_mfma2_kernel(const unsigned short* __restrict__ gin,
                       const int* __restrict__ list, const int* __restrict__ cnt, int cidx,
                       const unsigned short* __restrict__ wg,    // [9][COUT][3*CIN]
                       const float* __restrict__ bias,
                       unsigned short* __restrict__ gout){
  constexpr int KW = 3*CIN;
  constexpr int BP = KW + 8;
  constexpr int NT = COUT/16;
  constexpr int KT = KW/32;
  constexpr int PREN = (COUT*KW + BS*8 - 1)/(BS*8);
  __shared__ __align__(16) unsigned short B[2][COUT*BP];

  int nrows = cnt[cidx];
  int row0 = blockIdx.x*64;
  if (row0 >= nrows) return;

  int t = threadIdx.x;
  int lane = t & 63, wave = t >> 6;
  int m = lane & 15, quad = lane >> 4;

  #pragma unroll
  for (int i=0;i<PREN;i++){
    int e = t*8 + i*BS*8;
    if (e < COUT*KW){
      int n = e / KW, c = e - n*KW;
      *(uint4*)(&B[0][n*BP + c]) = *(const uint4*)(wg + e);
    }
  }

  int row = row0 + wave*16 + m;
  bool rv = row < nrows;
  int z=0, y=0, x=0;
  {
    int s = list[rv ? row : row0];
    z = s/(HO*WO); int rem = s - z*(HO*WO); y = rem/WO; x = rem - y*WO;
  }

  auto loadA = [&](int g, bf16x8* av){
    int dz = g/3, dy = g - dz*3;
    int zz = STR*z - PZ + dz, yy = STR*y - PY + dy, xx0 = STR*x - PX;
    bool zyok = rv && (unsigned)zz < (unsigned)DI && (unsigned)yy < (unsigned)HI;
    int base = ((zz*HI + yy)*WI + xx0)*CIN;
    #pragma unroll
    for (int kt=0; kt<KT; kt++){
      int tapx = (kt*32)/CIN;
      av[kt] = (bf16x8){0,0,0,0,0,0,0,0};
      if (zyok && (unsigned)(xx0 + tapx) < (unsigned)WI)
        av[kt] = *(const bf16x8*)(gin + (size_t)(base + kt*32 + quad*8));
    }
  };

  f32x4 acc[NT];
  #pragma unroll
  for (int i=0;i<NT;i++) acc[i] = (f32x4){0.f,0.f,0.f,0.f};

  bf16x8 acur[KT], anext[KT];
  loadA(0, acur);
  __syncthreads();

  #pragma unroll
  for (int g=0; g<9; g++){
    uint4 pre[PREN];
    if (g < 8){
      const unsigned short* src = wg + (size_t)(g+1)*COUT*KW;
      #pragma unroll
      for (int i=0;i<PREN;i++){
        int e = t*8 + i*BS*8;
        pre[i] = (e < COUT*KW) ? *(const uint4*)(src + e) : (uint4){0,0,0,0};
      }
      loadA(g+1, anext);
    }
    #pragma unroll
    for (int kt=0; kt<KT; kt++){
      #pragma unroll
      for (int nt=0; nt<NT; nt++){
        bf16x8 b = *(const bf16x8*)(&B[g&1][(nt*16 + m)*BP + kt*32 + quad*8]);
        acc[nt] = __builtin_amdgcn_mfma_f32_16x16x32_bf16(acur[kt], b, acc[nt], 0, 0, 0);
      }
    }
    if (g < 8){
      #pragma unroll
      for (int i=0;i<PREN;i++){
        int e = t*8 + i*BS*8;
        if (e < COUT*KW){
          int n = e / KW, c = e - n*KW;
          *(uint4*)(&B[(g+1)&1][n*BP + c]) = pre[i];
        }
      }
      #pragma unroll
      for (int kt=0; kt<KT; kt++) acur[kt] = anext[kt];
    }
    __syncthreads();
  }

  #pragma unroll
  for (int nt=0; nt<NT; nt++){
    int cout = nt*16 + m;
    float bv = bias[cout];
    #pragma unroll
    for (int rg=0; rg<4; rg++){
      int rw = row0 + wave*16 + quad*4 + rg;
      if (rw < nrows){
        int s = list[rw];
        gout[(size_t)s*COUT + cout] = f2bf(fmaxf(acc[nt][rg] + bv, 0.f));
      }
    }
  }
}

// ---- TAP-PARALLEL dense-grid MFMA conv: 16 rows/block, 4 waves over supertaps ----
template<int CIN,int COUT,int DI,int HI,int WI,int HO,int WO,int PZ,int PY,int PX,int STR>
__global__ __launch_bounds__(256)
void conv_tp_kernel(const unsigned short* __restrict__ gin,
                    const int* __restrict__ list, const int* __restrict__ cnt, int cidx,
                    const unsigned short* __restrict__ wg,    // [9][COUT][3*CIN]
                    const float* __restrict__ bias,
                    unsigned short* __restrict__ gout){
  constexpr int KW = 3*CIN;
  constexpr int NT = COUT/16;
  constexpr int KT = KW/32;
  __shared__ float R[4][NT*256];

  int nrows = cnt[cidx];
  int row0 = blockIdx.x*16;
  if (row0 >= nrows) return;

  int t = threadIdx.x;
  int lane = t & 63, wave = t >> 6;
  int m = lane & 15, quad = lane >> 4;

  int row = row0 + m;
  bool rv = row < nrows;
  int z=0, y=0, x=0;
  {
    int s = list[rv ? row : row0];
    z = s/(HO*WO); int rem = s - z*(HO*WO); y = rem/WO; x = rem - y*WO;
  }

  bf16x8 av[3][KT];
  #pragma unroll
  for (int i=0;i<3;i++){
    int g = wave + i*4;
    #pragma unroll
    for (int kt=0; kt<KT; kt++) av[i][kt] = (bf16x8){0,0,0,0,0,0,0,0};
    if (g < 9){
      int dz = g/3, dy = g - dz*3;
      int zz = STR*z - PZ + dz, yy = STR*y - PY + dy, xx0 = STR*x - PX;
      bool zyok = rv && (unsigned)zz < (unsigned)DI && (unsigned)yy < (unsigned)HI;
      int base = ((zz*HI + yy)*WI + xx0)*CIN;
      #pragma unroll
      for (int kt=0; kt<KT; kt++){
        int tapx = (kt*32)/CIN;
        if (zyok && (unsigned)(xx0 + tapx) < (unsigned)WI)
          av[i][kt] = *(const bf16x8*)(gin + (size_t)(base + kt*32 + quad*8));
      }
    }
  }

  f32x4 acc[NT];
  #pragma unroll
  for (int i=0;i<NT;i++) acc[i] = (f32x4){0.f,0.f,0.f,0.f};

  #pragma unroll
  for (int i=0;i<3;i++){
    int g = wave + i*4;
    if (g < 9){
      const unsigned short* wsrc = wg + (size_t)g*COUT*KW;
      #pragma unroll
      for (int kt=0; kt<KT; kt++){
        #pragma unroll
        for (int nt=0; nt<NT; nt++){
          bf16x8 b = *(const bf16x8*)(wsrc + (size_t)(nt*16 + m)*KW + kt*32 + quad*8);
          acc[nt] = __builtin_amdgcn_mfma_f32_16x16x32_bf16(av[i][kt], b, acc[nt], 0, 0, 0);
        }
      }
    }
  }

  #pragma unroll
  for (int nt=0; nt<NT; nt++)
    #pragma unroll
    for (int rg=0; rg<4; rg++)
      R[wave][nt*256 + (quad*4+rg)*16 + m] = acc[nt][rg];
  __syncthreads();

  for (int e = t; e < 16*COUT; e += BS){
    int r = e / COUT, cout = e % COUT;
    int nt = cout >> 4, mm = cout & 15;
    int idx = nt*256 + r*16 + mm;
    float sum = R[0][idx] + R[1][idx] + R[2][idx] + R[3][idx];
    int rw = row0 + r;
    if (rw < nrows){
      int s = list[rw];
      gout[(size_t)s*COUT + cout] = f2bf(fmaxf(sum + bias[cout], 0.f));
    }
  }
}

// ---- final: spconv 64->128, k=(3,1,1), stride=(2,1,1), pad 0; write [1,256,25,22] f32 ----
__global__ void conv_out_kernel(const unsigned short* __restrict__ g4,
                                const float* __restrict__ m4,
                                const float* __restrict__ wt, const float* __restrict__ bias,
                                float* __restrict__ out){
  int t = blockIdx.x*BS + threadIdx.x;
  if (t >= 128*DOo*HOo*WOo) return;
  int cout = t & 127; int s = t >> 7;
  int d = s/(HOo*WOo); int r = s - d*(HOo*WOo); int h = r/WOo; int w = r - h*WOo;
  float res = 0.f;
  bool act = false;
  float acc = bias[cout];
  for (int dz=0; dz<3; dz++){
    int z4 = 2*d + dz;
    int site = (z4*H4 + h)*W4 + w;
    if (m4[site] == 0.f) continue;
    act = true;
    const uint4* fr = (const uint4*)(g4 + (size_t)site*64);
    const float* wk = wt + dz*64*128 + cout;
    #pragma unroll
    for (int q=0; q<8; q++) acc8(acc, fr[q], wk + q*8*128, 128);
  }
  if (act) res = fmaxf(acc, 0.f);
  out[((cout*DOo + d)*HOo + h)*WOo + w] = res;
}

extern "C" void kernel_launch(void* const* d_in, const int* in_sizes, int n_in,
                              void* d_out, int out_size, void* d_ws, size_t ws_size,
                              hipStream_t stream){
  const float* x    = (const float*)d_in[0];
  const float* mask = (const float*)d_in[1];
  const float* w[12]; const float* bnp[12];
  for (int i=0;i<12;i++){ w[i]=(const float*)d_in[2+2*i]; bnp[i]=(const float*)d_in[3+2*i]; }

  char* base = (char*)d_ws; size_t off = 0;
  auto alloc = [&](size_t b)->void*{ void* p = base + off; off = (off + b + 255) & ~(size_t)255; return p; };

  // --- region zeroed every call (one memset) ---
  int* cnt   = (int*)alloc(16);                         // [c1,c2,c3,c4]
  int* I1    = (int*)alloc((size_t)N1v*4);              // site -> row+1 (0 = inactive)
  unsigned short* g2a = (unsigned short*)alloc((size_t)N2v*32*2);
  unsigned short* g2b = (unsigned short*)alloc((size_t)N2v*32*2);
  unsigned short* g3a = (unsigned short*)alloc((size_t)N3v*64*2);
  unsigned short* g3b = (unsigned short*)alloc((size_t)N3v*64*2);
  unsigned short* g4a = (unsigned short*)alloc((size_t)N4v*64*2);
  unsigned short* g4b = (unsigned short*)alloc((size_t)N4v*64*2);
  float* m2 = (float*)alloc((size_t)N2v*4);             // scatter-marked -> must be 0-init
  float* m3 = (float*)alloc((size_t)N3v*4);
  float* m4 = (float*)alloc((size_t)N4v*4);
  size_t zero_bytes = off;
  // --- fully-overwritten-before-read buffers ---
  unsigned short* xcl = (unsigned short*)alloc((size_t)N1v*4*2);  // channel-last bf16 x
  int* list1 = (int*)alloc((size_t)ROWS1*4);
  unsigned short* f1a = (unsigned short*)alloc((size_t)ROWS1*16*2);
  unsigned short* f1b = (unsigned short*)alloc((size_t)ROWS1*16*2);
  int* list2 = (int*)alloc((size_t)N2v*4);
  int* list3 = (int*)alloc((size_t)N3v*4);
  int* list4 = (int*)alloc((size_t)N4v*4);

  static const int Oa[12]={16,16,32,32,32,64,64,64,64,64,64,128};
  static const int Ia[12]={ 4,16,16,32,32,32,64,64,64,64,64, 64};
  static const int Ka[12]={27,27,27,27,27,27,27,27,27,27,27,  3};
  static const int Ma[12]={ 0, 2, 2, 3, 3, 3, 3, 3, 3, 3, 3,  0};  // prep mode
  float* wt[12]; float* bs[12]; unsigned short* wbt[12];
  for (int i=0;i<12;i++){
    bs[i] = (float*)alloc((size_t)Oa[i]*4);
    wt[i]=nullptr; wbt[i]=nullptr;
    if (Ma[i]==0)      wt[i]  = (float*)alloc((size_t)Oa[i]*Ia[i]*Ka[i]*4);
    else if (Ma[i]==3) wbt[i] = (unsigned short*)alloc((size_t)Oa[i]*Ia[i]*27*2);
    else               wbt[i] = (unsigned short*)alloc((size_t)14*Oa[i]*32*2);
  }

  hipMemsetAsync(base, 0, zero_bytes, stream);

  // fused weight prep + level-1 compaction (+ m2 scatter)
  PrepArgs pa;
  pa.off[0] = 0;
  for (int i=0;i<12;i++){
    pa.w[i]=w[i]; pa.bn[i]=bnp[i]; pa.bias[i]=bs[i];
    pa.O[i]=Oa[i]; pa.I[i]=Ia[i]; pa.K[i]=Ka[i]; pa.mode[i]=Ma[i];
    pa.dst[i] = (Ma[i]==0) ? (void*)wt[i] : (void*)wbt[i];
    int tot = (Ma[i]==2) ? 14*Oa[i]*32 : Oa[i]*Ia[i]*Ka[i];
    pa.off[i+1] = pa.off[i] + tot;
  }
  int prepB = (pa.off[12]+BS-1)/BS;
  int listB = (N1v + BS*16 - 1)/(BS*16);
  prep_and_list_kernel<<<prepB + listB, BS, 0, stream>>>(pa, prepB, mask, x, xcl, I1, list1, cnt, m2);

  // level 1: subm 4->16 (thread-per-row, channel-last), then subm 16->16 (tap-parallel MFMA)
  subm_l0_kernel<<<(ROWS1+BS-1)/BS, BS, 0, stream>>>(xcl, list1, cnt, wt[0], bs[0], f1a);
  conv_tp_l1_kernel<16,H1,W1,1,1,1,1,false><<<(ROWS1+15)/16, 256, 0, stream>>>
      (f1a, I1, list1, cnt, 0, wbt[1], bs[1], f1b);

  // level-2 list (+ m3 scatter), then spconv 16->32 (tap-parallel) into zeroed dense grid
  compact_mask_kernel<N2v,H2,W2,D3,H3,W3,1,1,1,true><<<(N2v+BS-1)/BS, BS, 0, stream>>>(m2, list2, cnt+1, m3);
  conv_tp_l1_kernel<32,H2,W2,1,1,1,2,true><<<(N2v+15)/16, 256, 0, stream>>>
      (f1b, I1, list2, cnt, 1, wbt[2], bs[2], g2a);

  // level-2 subm convs (tap-parallel supertap MFMA), 32ch
  {
    int nb = (N2v + 15)/16;
    conv_tp_kernel<32,32,D2,H2,W2,H2,W2,1,1,1,1><<<nb, 256, 0, stream>>>(g2a, list2, cnt, 1, wbt[3], bs[3], g2b);
    conv_tp_kernel<32,32,D2,H2,W2,H2,W2,1,1,1,1><<<nb, 256, 0, stream>>>(g2b, list2, cnt, 1, wbt[4], bs[4], g2a);
  }

  // level-3 list (+ m4 scatter); spconv (tap-parallel) + subm convs (64-row)
  compact_mask_kernel<N3v,H3,W3,D4,H4,W4,0,1,1,true><<<(N3v+BS-1)/BS, BS, 0, stream>>>(m3, list3, cnt+2, m4);
  {
    conv_tp_kernel<32,64,D2,H2,W2,H3,W3,1,1,1,2><<<(N3v+15)/16, 256, 0, stream>>>(g2a, list3, cnt, 2, wbt[5], bs[5], g3a);
    int nb = (N3v + 63)/64;
    conv_mfma2_kernel<64,64,D3,H3,W3,H3,W3,1,1,1,1><<<nb, 256, 0, stream>>>(g3a, list3, cnt, 2, wbt[6], bs[6], g3b);
    conv_mfma2_kernel<64,64,D3,H3,W3,H3,W3,1,1,1,1><<<nb, 256, 0, stream>>>(g3b, list3, cnt, 2, wbt[7], bs[7], g3a);
  }

  // level-4 list; all level-4 convs tap-parallel
  compact_mask_kernel<N4v,H4,W4,1,1,1,0,0,0,false><<<(N4v+BS-1)/BS, BS, 0, stream>>>(m4, list4, cnt+3, nullptr);
  {
    int nb = (N4v + 15)/16;
    conv_tp_kernel<64,64,D3,H3,W3,H4,W4,0,1,1,2><<<nb, 256, 0, stream>>>(g3a, list4, cnt, 3, wbt[8], bs[8], g4a);
    conv_tp_kernel<64,64,D4,H4,W4,H4,W4,1,1,1,1><<<nb, 256, 0, stream>>>(g4a, list4, cnt, 3, wbt[9], bs[9], g4b);
    conv_tp_kernel<64,64,D4,H4,W4,H4,W4,1,1,1,1><<<nb, 256, 0, stream>>>(g4b, list4, cnt, 3, wbt[10], bs[10], g4a);
  }

  // final spconv (3,1,1)/(2,1,1)/pad0 -> [1,256,25,22]
  conv_out_kernel<<<(128*DOo*HOo*WOo)/BS, BS, 0, stream>>>(g4a, m4, wt[11], bs[11], (float*)d_out);
}

// Round 12
// 358.996 us; speedup vs baseline: 1.0716x; 1.0712x over previous
//
#include <hip/hip_runtime.h>

#define BS 256

// ---- problem dims ----
constexpr int D1=41, H1=200, W1=176; constexpr int N1v=D1*H1*W1;   // 1,443,200
constexpr int D2=21, H2=100, W2=88;  constexpr int N2v=D2*H2*W2;   //   184,800
constexpr int D3=11, H3=50,  W3=44;  constexpr int N3v=D3*H3*W3;   //    24,200
constexpr int D4=5,  H4=25,  W4=22;  constexpr int N4v=D4*H4*W4;   //     2,750
constexpr int DOo=2, HOo=25, WOo=22;                                // out spatial
constexpr int ROWS1=40960;   // cap on level-1 active sites (actual ~28.9k)

typedef __attribute__((ext_vector_type(8))) short bf16x8;
typedef __attribute__((ext_vector_type(4))) float f32x4;

// ---- bf16 helpers ----
__device__ __forceinline__ float bflo(unsigned int u){ return __uint_as_float(u<<16); }
__device__ __forceinline__ float bfhi(unsigned int u){ return __uint_as_float(u & 0xffff0000u); }
__device__ __forceinline__ unsigned short f2bf(float f){
  unsigned int x = __float_as_uint(f);
  x += 0x7fffu + ((x>>16)&1u);             // round-to-nearest-even
  return (unsigned short)(x>>16);
}
__device__ __forceinline__ void acc8(float& acc, uint4 p, const float* __restrict__ wk, int stride){
  acc = fmaf(bflo(p.x), wk[0*stride], acc);
  acc = fmaf(bfhi(p.x), wk[1*stride], acc);
  acc = fmaf(bflo(p.y), wk[2*stride], acc);
  acc = fmaf(bfhi(p.y), wk[3*stride], acc);
  acc = fmaf(bflo(p.z), wk[4*stride], acc);
  acc = fmaf(bfhi(p.z), wk[5*stride], acc);
  acc = fmaf(bflo(p.w), wk[6*stride], acc);
  acc = fmaf(bfhi(p.w), wk[7*stride], acc);
}

// ---- weight-prep parameter pack (BN folded) ----
// mode 0: f32, layout [k][ci][o]                 (layers 0, 11)
// mode 2: bf16 tap-pair packed [p][o][32]        (layers 1, 2 — l1 MFMA)
// mode 3: bf16 supertap [dzdy][o][dx*CIN+ci]     (layers 3..10 — dense MFMA)
struct PrepArgs {
  const float* w[12]; const float* bn[12];
  void* dst[12]; float* bias[12];
  int O[12], I[12], K[12], mode[12];
  int off[13];
};

// ---- FUSED: weight prep (blocks [0,prepB)) + level-1 compaction w/ m2 scatter ----
__global__ void prep_and_list_kernel(PrepArgs a, int prepB,
                                     const float* __restrict__ mask,
                                     const float* __restrict__ x,
                                     unsigned short* __restrict__ xcl,
                                     int* __restrict__ I1, int* __restrict__ list1,
                                     int* __restrict__ cnt, float* __restrict__ m2){
  if ((int)blockIdx.x < prepB){
    int t = blockIdx.x*BS + threadIdx.x;
    if (t >= a.off[12]) return;
    int li = 0;
    while (t >= a.off[li+1]) li++;
    int e = t - a.off[li];
    int O=a.O[li], I=a.I[li], K=a.K[li], mode=a.mode[li];
    const float* w = a.w[li]; const float* bn = a.bn[li];
    if (mode == 2){
      int p = e/(O*32); int rem = e - p*(O*32); int o = rem>>5; int kk = rem&31;
      int tap = 2*p + (kk>=16 ? 1 : 0); int ci = kk&15;
      float g=bn[o], b=bn[O+o], m=bn[2*O+o], v=bn[3*O+o];
      float sc = g*rsqrtf(v+1e-3f);
      float val = (tap < 27) ? w[(o*I+ci)*K + tap]*sc : 0.f;
      ((unsigned short*)a.dst[li])[e] = f2bf(val);
      if (p==0 && kk==0) a.bias[li][o] = b - m*sc;
    } else if (mode == 3){
      int ci = e % I; int tmp = e / I; int dx = tmp % 3; tmp /= 3; int o = tmp % O; int g9 = tmp / O;
      float g=bn[o], b=bn[O+o], m=bn[2*O+o], v=bn[3*O+o];
      float sc = g*rsqrtf(v+1e-3f);
      int tap = g9*3 + dx;
      ((unsigned short*)a.dst[li])[e] = f2bf(w[(o*I+ci)*27 + tap]*sc);
      if (g9==0 && dx==0 && ci==0) a.bias[li][o] = b - m*sc;
    } else {
      int k = e % K; int rest = e / K; int ci = rest % I; int o = rest / I;
      float g=bn[o], b=bn[O+o], m=bn[2*O+o], v=bn[3*O+o];
      float sc = g*rsqrtf(v+1e-3f);
      ((float*)a.dst[li])[(k*I+ci)*O + o] = w[(o*I+ci)*K + k]*sc;
      if (ci==0 && k==0) a.bias[li][o] = b - m*sc;
    }
    return;
  }
  // ---- level-1 compaction + x->channel-last + m2 scatter ----
  constexpr int PER = 16;
  __shared__ int sc_[BS]; __shared__ int sbase;
  int b = blockIdx.x - prepB, t = threadIdx.x;
  int base_s = b*BS*PER;
  unsigned int bits = 0; int c = 0;
  #pragma unroll
  for (int i=0;i<PER;i++){
    int s = base_s + i*BS + t;
    bool act = false;
    if (s < N1v){
      act = mask[s] > 0.f;
      unsigned short h0 = f2bf(x[s]),       h1 = f2bf(x[N1v+s]);
      unsigned short h2 = f2bf(x[2*N1v+s]), h3 = f2bf(x[3*N1v+s]);
      uint2 pk; pk.x = ((unsigned)h1<<16)|h0; pk.y = ((unsigned)h3<<16)|h2;
      *(uint2*)(xcl + (size_t)s*4) = pk;
    }
    bits |= (act?1u:0u) << i; c += act;
  }
  sc_[t] = c;
  __syncthreads();
  for (int ofs=1; ofs<BS; ofs<<=1){
    int v = (t>=ofs) ? sc_[t-ofs] : 0;
    __syncthreads();
    sc_[t] += v;
    __syncthreads();
  }
  if (t == BS-1) sbase = atomicAdd(cnt, sc_[t]);
  __syncthreads();
  int pos = sbase + sc_[t] - c;
  #pragma unroll
  for (int i=0;i<PER;i++){
    if (bits & (1u<<i)){
      int s = base_s + i*BS + t;
      list1[pos] = s; I1[s] = pos+1; pos++;
      int zz = s/(H1*W1); int rem = s - zz*(H1*W1); int yy = rem/W1; int xx = rem - yy*W1;
      int az = zz+1, ay = yy+1, ax = xx+1;
      int zlo = (az-2) <= 0 ? 0 : (az-1)/2;  int zhi = min(D2-1, az/2);
      int ylo = (ay-2) <= 0 ? 0 : (ay-1)/2;  int yhi = min(H2-1, ay/2);
      int xlo = (ax-2) <= 0 ? 0 : (ax-1)/2;  int xhi = min(W2-1, ax/2);
      for (int zo=zlo; zo<=zhi; zo++)
        for (int yo=ylo; yo<=yhi; yo++)
          for (int xo=xlo; xo<=xhi; xo++)
            m2[(zo*H2+yo)*W2+xo] = 1.f;
    }
  }
}

// ---- compact 0/1 mask grid into a list; optionally scatter next-level mask ----
template<int N,int HI,int WI,int DON,int HON,int WON,int PZ,int PY,int PX,bool SCAT>
__global__ void compact_mask_kernel(const float* __restrict__ mout,
                                    int* __restrict__ list, int* __restrict__ cnt1,
                                    float* __restrict__ mnext){
  __shared__ int sc[BS]; __shared__ int sbase;
  int b = blockIdx.x, t = threadIdx.x;
  int s = b*BS + t;
  bool act = (s < N) && (mout[s] > 0.f);
  int c = act ? 1 : 0;
  sc[t] = c;
  __syncthreads();
  for (int ofs=1; ofs<BS; ofs<<=1){
    int v = (t>=ofs) ? sc[t-ofs] : 0;
    __syncthreads();
    sc[t] += v;
    __syncthreads();
  }
  if (t == BS-1) sbase = atomicAdd(cnt1, sc[t]);
  __syncthreads();
  if (act){
    list[sbase + sc[t] - 1] = s;
    if (SCAT){
      int zz = s/(HI*WI); int rem = s - zz*(HI*WI); int yy = rem/WI; int xx = rem - yy*WI;
      int az = zz+PZ, ay = yy+PY, ax = xx+PX;
      int zlo = (az-2) <= 0 ? 0 : (az-1)/2;  int zhi = min(DON-1, az/2);
      int ylo = (ay-2) <= 0 ? 0 : (ay-1)/2;  int yhi = min(HON-1, ay/2);
      int xlo = (ax-2) <= 0 ? 0 : (ax-1)/2;  int xhi = min(WON-1, ax/2);
      for (int zo=zlo; zo<=zhi; zo++)
        for (int yo=ylo; yo<=yhi; yo++)
          for (int xo=xlo; xo<=xhi; xo++)
            mnext[(zo*HON+yo)*WON+xo] = 1.f;
    }
  }
}

// ---- layer 0: subm conv 4->16, one THREAD per row, channel-last bf16 input ----
__global__ void subm_l0_kernel(const unsigned short* __restrict__ xcl,
                               const int* __restrict__ list1, const int* __restrict__ cnt,
                               const float* __restrict__ wt, const float* __restrict__ bias,
                               unsigned short* __restrict__ fout){
  __shared__ float Wl[27*4*16];
  __shared__ float Bl[16];
  int t = threadIdx.x;
  for (int e=t; e<27*4*16; e+=BS) Wl[e] = wt[e];
  if (t < 16) Bl[t] = bias[t];
  __syncthreads();
  int row = blockIdx.x*BS + t;
  if (row >= cnt[0]) return;
  int s = list1[row];
  int z = s/(H1*W1); int r = s - z*(H1*W1); int y = r/W1; int xx = r - y*W1;
  float acc[16];
  #pragma unroll
  for (int o=0;o<16;o++) acc[o] = Bl[o];
  #pragma unroll
  for (int dz=-1; dz<=1; dz++){ int zz=z+dz; if ((unsigned)zz >= (unsigned)D1) continue;
    #pragma unroll
    for (int dy=-1; dy<=1; dy++){ int yy=y+dy; if ((unsigned)yy >= (unsigned)H1) continue;
      #pragma unroll
      for (int dx=-1; dx<=1; dx++){ int xc=xx+dx; if ((unsigned)xc >= (unsigned)W1) continue;
        int ns = (zz*H1+yy)*W1+xc;
        int k = ((dz+1)*3+(dy+1))*3+(dx+1);
        uint2 pk = *(const uint2*)(xcl + (size_t)ns*4);
        float x0 = bflo(pk.x), x1 = bfhi(pk.x), x2 = bflo(pk.y), x3 = bfhi(pk.y);
        const float* wk = Wl + k*64;
        #pragma unroll
        for (int o=0;o<16;o++)
          acc[o] = fmaf(x0, wk[o], fmaf(x1, wk[16+o], fmaf(x2, wk[32+o], fmaf(x3, wk[48+o], acc[o]))));
      }}}
  #pragma unroll
  for (int o=0;o<16;o++) fout[row*16+o] = f2bf(fmaxf(acc[o], 0.f));
}

// ---- level-1 MFMA conv: I1 lookups hoisted, fin loads pipelined by 1 ----
template<int COUT,int HO,int WO,int PZ,int PY,int PX,int STR,bool DENSE_OUT>
__global__ __launch_bounds__(256)
void conv_mfma_l1_kernel(const unsigned short* __restrict__ fin,   // compact [row][16]
                         const int* __restrict__ I1,
                         const int* __restrict__ list, const int* __restrict__ cnt, int cidx,
                         const unsigned short* __restrict__ wbt,   // [14][COUT][32]
                         const float* __restrict__ bias,
                         unsigned short* __restrict__ outp){
  constexpr int BP = 40;                   // padded LDS row stride (shorts)
  constexpr int NT = COUT/16;
  __shared__ __align__(16) unsigned short B[14*COUT*BP];

  int nrows = cnt[cidx];
  int row0 = blockIdx.x*64;
  if (row0 >= nrows) return;

  int t = threadIdx.x;
  int lane = t & 63, wave = t >> 6;
  int m = lane & 15, quad = lane >> 4;

  constexpr int TOT = 14*COUT*32;
  for (int e = t*8; e < TOT; e += BS*8){
    int n = e >> 5, c = e & 31;
    *(uint4*)(&B[n*BP + c]) = *(const uint4*)(wbt + e);
  }

  int row = row0 + wave*16 + m;
  bool rv = row < nrows;
  int z=0, y=0, x=0;
  {
    int s = list[rv ? row : row0];
    z = s/(HO*WO); int rem = s - z*(HO*WO); y = rem/WO; x = rem - y*WO;
  }

  int rr[14];
  #pragma unroll
  for (int p=0;p<14;p++){
    int tap = 2*p + (quad>>1);
    rr[p] = 0;
    if (rv && tap < 27){
      int dz = tap/9, rem = tap - dz*9, dy = rem/3, dx = rem - dy*3;
      int zz = STR*z - PZ + dz, yy = STR*y - PY + dy, xx = STR*x - PX + dx;
      if ((unsigned)zz < (unsigned)D1 && (unsigned)yy < (unsigned)H1 && (unsigned)xx < (unsigned)W1)
        rr[p] = I1[(zz*H1+yy)*W1+xx];
    }
  }
  __syncthreads();

  f32x4 acc[NT];
  #pragma unroll
  for (int i=0;i<NT;i++) acc[i] = (f32x4){0.f,0.f,0.f,0.f};

  bf16x8 acur = (bf16x8){0,0,0,0,0,0,0,0};
  if (rr[0] > 0) acur = *(const bf16x8*)(fin + (size_t)(rr[0]-1)*16 + (quad&1)*8);
  #pragma unroll
  for (int p=0;p<14;p++){
    bf16x8 anext = (bf16x8){0,0,0,0,0,0,0,0};
    if (p < 13 && rr[p+1] > 0)
      anext = *(const bf16x8*)(fin + (size_t)(rr[p+1]-1)*16 + (quad&1)*8);
    #pragma unroll
    for (int nt=0; nt<NT; nt++){
      bf16x8 b = *(const bf16x8*)(&B[(p*COUT + nt*16 + m)*BP + quad*8]);
      acc[nt] = __builtin_amdgcn_mfma_f32_16x16x32_bf16(acur, b, acc[nt], 0, 0, 0);
    }
    acur = anext;
  }

  #pragma unroll
  for (int nt=0; nt<NT; nt++){
    int cout = nt*16 + m;
    float bv = bias[cout];
    #pragma unroll
    for (int rg=0; rg<4; rg++){
      int rw = row0 + wave*16 + quad*4 + rg;
      if (rw < nrows){
        float v = fmaxf(acc[nt][rg] + bv, 0.f);
        if (DENSE_OUT){
          int s = list[rw];
          outp[(size_t)s*COUT + cout] = f2bf(v);
        } else {
          outp[(size_t)rw*COUT + cout] = f2bf(v);
        }
      }
    }
  }
}

// ---- dense-grid MFMA conv, 64 rows/block, A+B pipelined by 1 (levels 2,3 subm) ----
template<int CIN,int COUT,int DI,int HI,int WI,int HO,int WO,int PZ,int PY,int PX,int STR>
__global__ __launch_bounds__(256)
void conv_mfma2_kernel(const unsigned short* __restrict__ gin,
                       const int* __restrict__ list, const int* __restrict__ cnt, int cidx,
                       const unsigned short* __restrict__ wg,    // [9][COUT][3*CIN]
                       const float* __restrict__ bias,
                       unsigned short* __restrict__ gout){
  constexpr int KW = 3*CIN;
  constexpr int BP = KW + 8;
  constexpr int NT = COUT/16;
  constexpr int KT = KW/32;
  constexpr int PREN = (COUT*KW + BS*8 - 1)/(BS*8);
  __shared__ __align__(16) unsigned short B[2][COUT*BP];

  int nrows = cnt[cidx];
  int row0 = blockIdx.x*64;
  if (row0 >= nrows) return;

  int t = threadIdx.x;
  int lane = t & 63, wave = t >> 6;
  int m = lane & 15, quad = lane >> 4;

  #pragma unroll
  for (int i=0;i<PREN;i++){
    int e = t*8 + i*BS*8;
    if (e < COUT*KW){
      int n = e / KW, c = e - n*KW;
      *(uint4*)(&B[0][n*BP + c]) = *(const uint4*)(wg + e);
    }
  }

  int row = row0 + wave*16 + m;
  bool rv = row < nrows;
  int z=0, y=0, x=0;
  {
    int s = list[rv ? row : row0];
    z = s/(HO*WO); int rem = s - z*(HO*WO); y = rem/WO; x = rem - y*WO;
  }

  auto loadA = [&](int g, bf16x8* av){
    int dz = g/3, dy = g - dz*3;
    int zz = STR*z - PZ + dz, yy = STR*y - PY + dy, xx0 = STR*x - PX;
    bool zyok = rv && (unsigned)zz < (unsigned)DI && (unsigned)yy < (unsigned)HI;
    int base = ((zz*HI + yy)*WI + xx0)*CIN;
    #pragma unroll
    for (int kt=0; kt<KT; kt++){
      int tapx = (kt*32)/CIN;
      av[kt] = (bf16x8){0,0,0,0,0,0,0,0};
      if (zyok && (unsigned)(xx0 + tapx) < (unsigned)WI)
        av[kt] = *(const bf16x8*)(gin + (size_t)(base + kt*32 + quad*8));
    }
  };

  f32x4 acc[NT];
  #pragma unroll
  for (int i=0;i<NT;i++) acc[i] = (f32x4){0.f,0.f,0.f,0.f};

  bf16x8 acur[KT], anext[KT];
  loadA(0, acur);
  __syncthreads();

  #pragma unroll
  for (int g=0; g<9; g++){
    uint4 pre[PREN];
    if (g < 8){
      const unsigned short* src = wg + (size_t)(g+1)*COUT*KW;
      #pragma unroll
      for (int i=0;i<PREN;i++){
        int e = t*8 + i*BS*8;
        pre[i] = (e < COUT*KW) ? *(const uint4*)(src + e) : (uint4){0,0,0,0};
      }
      loadA(g+1, anext);
    }
    #pragma unroll
    for (int kt=0; kt<KT; kt++){
      #pragma unroll
      for (int nt=0; nt<NT; nt++){
        bf16x8 b = *(const bf16x8*)(&B[g&1][(nt*16 + m)*BP + kt*32 + quad*8]);
        acc[nt] = __builtin_amdgcn_mfma_f32_16x16x32_bf16(acur[kt], b, acc[nt], 0, 0, 0);
      }
    }
    if (g < 8){
      #pragma unroll
      for (int i=0;i<PREN;i++){
        int e = t*8 + i*BS*8;
        if (e < COUT*KW){
          int n = e / KW, c = e - n*KW;
          *(uint4*)(&B[(g+1)&1][n*BP + c]) = pre[i];
        }
      }
      #pragma unroll
      for (int kt=0; kt<KT; kt++) acur[kt] = anext[kt];
    }
    __syncthreads();
  }

  #pragma unroll
  for (int nt=0; nt<NT; nt++){
    int cout = nt*16 + m;
    float bv = bias[cout];
    #pragma unroll
    for (int rg=0; rg<4; rg++){
      int rw = row0 + wave*16 + quad*4 + rg;
      if (rw < nrows){
        int s = list[rw];
        gout[(size_t)s*COUT + cout] = f2bf(fmaxf(acc[nt][rg] + bv, 0.f));
      }
    }
  }
}

// ---- TAP-PARALLEL dense-grid MFMA conv: 16 rows/block, 4 waves over supertaps ----
template<int CIN,int COUT,int DI,int HI,int WI,int HO,int WO,int PZ,int PY,int PX,int STR>
__global__ __launch_bounds__(256)
void conv_tp_kernel(const unsigned short* __restrict__ gin,
                    const int* __restrict__ list, const int* __restrict__ cnt, int cidx,
                    const unsigned short* __restrict__ wg,    // [9][COUT][3*CIN]
                    const float* __restrict__ bias,
                    unsigned short* __restrict__ gout){
  constexpr int KW = 3*CIN;
  constexpr int NT = COUT/16;
  constexpr int KT = KW/32;
  __shared__ float R[4][NT*256];

  int nrows = cnt[cidx];
  int row0 = blockIdx.x*16;
  if (row0 >= nrows) return;

  int t = threadIdx.x;
  int lane = t & 63, wave = t >> 6;
  int m = lane & 15, quad = lane >> 4;

  int row = row0 + m;
  bool rv = row < nrows;
  int z=0, y=0, x=0;
  {
    int s = list[rv ? row : row0];
    z = s/(HO*WO); int rem = s - z*(HO*WO); y = rem/WO; x = rem - y*WO;
  }

  bf16x8 av[3][KT];
  #pragma unroll
  for (int i=0;i<3;i++){
    int g = wave + i*4;
    #pragma unroll
    for (int kt=0; kt<KT; kt++) av[i][kt] = (bf16x8){0,0,0,0,0,0,0,0};
    if (g < 9){
      int dz = g/3, dy = g - dz*3;
      int zz = STR*z - PZ + dz, yy = STR*y - PY + dy, xx0 = STR*x - PX;
      bool zyok = rv && (unsigned)zz < (unsigned)DI && (unsigned)yy < (unsigned)HI;
      int base = ((zz*HI + yy)*WI + xx0)*CIN;
      #pragma unroll
      for (int kt=0; kt<KT; kt++){
        int tapx = (kt*32)/CIN;
        if (zyok && (unsigned)(xx0 + tapx) < (unsigned)WI)
          av[i][kt] = *(const bf16x8*)(gin + (size_t)(base + kt*32 + quad*8));
      }
    }
  }

  f32x4 acc[NT];
  #pragma unroll
  for (int i=0;i<NT;i++) acc[i] = (f32x4){0.f,0.f,0.f,0.f};

  #pragma unroll
  for (int i=0;i<3;i++){
    int g = wave + i*4;
    if (g < 9){
      const unsigned short* wsrc = wg + (size_t)g*COUT*KW;
      #pragma unroll
      for (int kt=0; kt<KT; kt++){
        #pragma unroll
        for (int nt=0; nt<NT; nt++){
          bf16x8 b = *(const bf16x8*)(wsrc + (size_t)(nt*16 + m)*KW + kt*32 + quad*8);
          acc[nt] = __builtin_amdgcn_mfma_f32_16x16x32_bf16(av[i][kt], b, acc[nt], 0, 0, 0);
        }
      }
    }
  }

  #pragma unroll
  for (int nt=0; nt<NT; nt++)
    #pragma unroll
    for (int rg=0; rg<4; rg++)
      R[wave][nt*256 + (quad*4+rg)*16 + m] = acc[nt][rg];
  __syncthreads();

  for (int e = t; e < 16*COUT; e += BS){
    int r = e / COUT, cout = e % COUT;
    int nt = cout >> 4, mm = cout & 15;
    int idx = nt*256 + r*16 + mm;
    float sum = R[0][idx] + R[1][idx] + R[2][idx] + R[3][idx];
    int rw = row0 + r;
    if (rw < nrows){
      int s = list[rw];
      gout[(size_t)s*COUT + cout] = f2bf(fmaxf(sum + bias[cout], 0.f));
    }
  }
}

// ---- final: spconv 64->128, k=(3,1,1), stride=(2,1,1), pad 0; write [1,256,25,22] f32 ----
__global__ void conv_out_kernel(const unsigned short* __restrict__ g4,
                                const float* __restrict__ m4,
                                const float* __restrict__ wt, const float* __restrict__ bias,
                                float* __restrict__ out){
  int t = blockIdx.x*BS + threadIdx.x;
  if (t >= 128*DOo*HOo*WOo) return;
  int cout = t & 127; int s = t >> 7;
  int d = s/(HOo*WOo); int r = s - d*(HOo*WOo); int h = r/WOo; int w = r - h*WOo;
  float res = 0.f;
  bool act = false;
  float acc = bias[cout];
  for (int dz=0; dz<3; dz++){
    int z4 = 2*d + dz;
    int site = (z4*H4 + h)*W4 + w;
    if (m4[site] == 0.f) continue;
    act = true;
    const uint4* fr = (const uint4*)(g4 + (size_t)site*64);
    const float* wk = wt + dz*64*128 + cout;
    #pragma unroll
    for (int q=0; q<8; q++) acc8(acc, fr[q], wk + q*8*128, 128);
  }
  if (act) res = fmaxf(acc, 0.f);
  out[((cout*DOo + d)*HOo + h)*WOo + w] = res;
}

extern "C" void kernel_launch(void* const* d_in, const int* in_sizes, int n_in,
                              void* d_out, int out_size, void* d_ws, size_t ws_size,
                              hipStream_t stream){
  const float* x    = (const float*)d_in[0];
  const float* mask = (const float*)d_in[1];
  const float* w[12]; const float* bnp[12];
  for (int i=0;i<12;i++){ w[i]=(const float*)d_in[2+2*i]; bnp[i]=(const float*)d_in[3+2*i]; }

  char* base = (char*)d_ws; size_t off = 0;
  auto alloc = [&](size_t b)->void*{ void* p = base + off; off = (off + b + 255) & ~(size_t)255; return p; };

  // --- region zeroed every call (one memset) ---
  int* cnt   = (int*)alloc(16);                         // [c1,c2,c3,c4]
  int* I1    = (int*)alloc((size_t)N1v*4);              // site -> row+1 (0 = inactive)
  unsigned short* g2a = (unsigned short*)alloc((size_t)N2v*32*2);
  unsigned short* g2b = (unsigned short*)alloc((size_t)N2v*32*2);
  unsigned short* g3a = (unsigned short*)alloc((size_t)N3v*64*2);
  unsigned short* g3b = (unsigned short*)alloc((size_t)N3v*64*2);
  unsigned short* g4a = (unsigned short*)alloc((size_t)N4v*64*2);
  unsigned short* g4b = (unsigned short*)alloc((size_t)N4v*64*2);
  float* m2 = (float*)alloc((size_t)N2v*4);             // scatter-marked -> must be 0-init
  float* m3 = (float*)alloc((size_t)N3v*4);
  float* m4 = (float*)alloc((size_t)N4v*4);
  size_t zero_bytes = off;
  // --- fully-overwritten-before-read buffers ---
  unsigned short* xcl = (unsigned short*)alloc((size_t)N1v*4*2);  // channel-last bf16 x
  int* list1 = (int*)alloc((size_t)ROWS1*4);
  unsigned short* f1a = (unsigned short*)alloc((size_t)ROWS1*16*2);
  unsigned short* f1b = (unsigned short*)alloc((size_t)ROWS1*16*2);
  int* list2 = (int*)alloc((size_t)N2v*4);
  int* list3 = (int*)alloc((size_t)N3v*4);
  int* list4 = (int*)alloc((size_t)N4v*4);

  static const int Oa[12]={16,16,32,32,32,64,64,64,64,64,64,128};
  static const int Ia[12]={ 4,16,16,32,32,32,64,64,64,64,64, 64};
  static const int Ka[12]={27,27,27,27,27,27,27,27,27,27,27,  3};
  static const int Ma[12]={ 0, 2, 2, 3, 3, 3, 3, 3, 3, 3, 3,  0};  // prep mode
  float* wt[12]; float* bs[12]; unsigned short* wbt[12];
  for (int i=0;i<12;i++){
    bs[i] = (float*)alloc((size_t)Oa[i]*4);
    wt[i]=nullptr; wbt[i]=nullptr;
    if (Ma[i]==0)      wt[i]  = (float*)alloc((size_t)Oa[i]*Ia[i]*Ka[i]*4);
    else if (Ma[i]==3) wbt[i] = (unsigned short*)alloc((size_t)Oa[i]*Ia[i]*27*2);
    else               wbt[i] = (unsigned short*)alloc((size_t)14*Oa[i]*32*2);
  }

  hipMemsetAsync(base, 0, zero_bytes, stream);

  // fused weight prep + level-1 compaction (+ m2 scatter)
  PrepArgs pa;
  pa.off[0] = 0;
  for (int i=0;i<12;i++){
    pa.w[i]=w[i]; pa.bn[i]=bnp[i]; pa.bias[i]=bs[i];
    pa.O[i]=Oa[i]; pa.I[i]=Ia[i]; pa.K[i]=Ka[i]; pa.mode[i]=Ma[i];
    pa.dst[i] = (Ma[i]==0) ? (void*)wt[i] : (void*)wbt[i];
    int tot = (Ma[i]==2) ? 14*Oa[i]*32 : Oa[i]*Ia[i]*Ka[i];
    pa.off[i+1] = pa.off[i] + tot;
  }
  int prepB = (pa.off[12]+BS-1)/BS;
  int listB = (N1v + BS*16 - 1)/(BS*16);
  prep_and_list_kernel<<<prepB + listB, BS, 0, stream>>>(pa, prepB, mask, x, xcl, I1, list1, cnt, m2);

  // level 1: subm 4->16 (thread-per-row, channel-last), then subm 16->16 MFMA
  subm_l0_kernel<<<(ROWS1+BS-1)/BS, BS, 0, stream>>>(xcl, list1, cnt, wt[0], bs[0], f1a);
  conv_mfma_l1_kernel<16,H1,W1,1,1,1,1,false><<<ROWS1/64, 256, 0, stream>>>
      (f1a, I1, list1, cnt, 0, wbt[1], bs[1], f1b);

  // level-2 list (+ m3 scatter), then spconv 16->32 into zeroed dense grid
  compact_mask_kernel<N2v,H2,W2,D3,H3,W3,1,1,1,true><<<(N2v+BS-1)/BS, BS, 0, stream>>>(m2, list2, cnt+1, m3);
  conv_mfma_l1_kernel<32,H2,W2,1,1,1,2,true><<<(N2v+63)/64, 256, 0, stream>>>
      (f1b, I1, list2, cnt, 1, wbt[2], bs[2], g2a);

  // level-2 subm convs (64-row MFMA), 32ch
  {
    int nb = (N2v + 63)/64;
    conv_mfma2_kernel<32,32,D2,H2,W2,H2,W2,1,1,1,1><<<nb, 256, 0, stream>>>(g2a, list2, cnt, 1, wbt[3], bs[3], g2b);
    conv_mfma2_kernel<32,32,D2,H2,W2,H2,W2,1,1,1,1><<<nb, 256, 0, stream>>>(g2b, list2, cnt, 1, wbt[4], bs[4], g2a);
  }

  // level-3 list (+ m4 scatter); spconv (tap-parallel) + subm convs (64-row)
  compact_mask_kernel<N3v,H3,W3,D4,H4,W4,0,1,1,true><<<(N3v+BS-1)/BS, BS, 0, stream>>>(m3, list3, cnt+2, m4);
  {
    conv_tp_kernel<32,64,D2,H2,W2,H3,W3,1,1,1,2><<<(N3v+15)/16, 256, 0, stream>>>(g2a, list3, cnt, 2, wbt[5], bs[5], g3a);
    int nb = (N3v + 63)/64;
    conv_mfma2_kernel<64,64,D3,H3,W3,H3,W3,1,1,1,1><<<nb, 256, 0, stream>>>(g3a, list3, cnt, 2, wbt[6], bs[6], g3b);
    conv_mfma2_kernel<64,64,D3,H3,W3,H3,W3,1,1,1,1><<<nb, 256, 0, stream>>>(g3b, list3, cnt, 2, wbt[7], bs[7], g3a);
  }

  // level-4 list; all level-4 convs tap-parallel
  compact_mask_kernel<N4v,H4,W4,1,1,1,0,0,0,false><<<(N4v+BS-1)/BS, BS, 0, stream>>>(m4, list4, cnt+3, nullptr);
  {
    int nb = (N4v + 15)/16;
    conv_tp_kernel<64,64,D3,H3,W3,H4,W4,0,1,1,2><<<nb, 256, 0, stream>>>(g3a, list4, cnt, 3, wbt[8], bs[8], g4a);
    conv_tp_kernel<64,64,D4,H4,W4,H4,W4,1,1,1,1><<<nb, 256, 0, stream>>>(g4a, list4, cnt, 3, wbt[9], bs[9], g4b);
    conv_tp_kernel<64,64,D4,H4,W4,H4,W4,1,1,1,1><<<nb, 256, 0, stream>>>(g4b, list4, cnt, 3, wbt[10], bs[10], g4a);
  }

  // final spconv (3,1,1)/(2,1,1)/pad0 -> [1,256,25,22]
  conv_out_kernel<<<(128*DOo*HOo*WOo)/BS, BS, 0, stream>>>(g4a, m4, wt[11], bs[11], (float*)d_out);
}